// Round 3
// baseline (3818.627 us; speedup 1.0000x reference)
//
#include <hip/hip_runtime.h>
#include <hip/hip_bf16.h>
#include <math.h>

// Problem constants
#define NSEQ 2048
#define TT   128
#define EE   128
#define HH   256
#define GG   1024      // 4*H gate rows
#define LL   1000
#define BS   32        // sequences per block (2 MFMA col-groups of 16)
#define NT   512       // threads per block (8 waves)
#define NBLK (NSEQ / BS)   // 64 blocks
#define NKT  12        // K tiles of 32: 4 (x: E=128) + 8 (h: H=256)
#define NMT  64        // M tiles of 16: 1024 gate rows
#define NKT_O 8        // K tiles for output GEMM (H=256)
#define WSA_ELEMS (NMT * NKT * 64 * 8)      // 768 KB bf16
#define WSO_ELEMS (NMT * NKT_O * 64 * 8)    // 512 KB bf16

typedef __attribute__((ext_vector_type(8))) short bf16x8;
typedef __attribute__((ext_vector_type(4))) float f32x4;

__device__ __forceinline__ unsigned short f2bf(float f) {
    union { float f; unsigned u; } v; v.f = f;
    unsigned r = v.u + 0x7FFF + ((v.u >> 16) & 1);   // RNE
    return (unsigned short)(r >> 16);
}
__device__ __forceinline__ float sigf(float x) { return 1.0f / (1.0f + __expf(-x)); }
__device__ __forceinline__ float tanh_fast(float x) { return 1.0f - 2.0f / (1.0f + __expf(2.0f * x)); }

__global__ void init_out_kernel(float* out) {
    int i = blockIdx.x * blockDim.x + threadIdx.x;
    if (i < HH + 1) out[i] = 0.0f;
}

// Pre-shuffle weights into MFMA A-fragment order, bf16 (same layout as R2).
__global__ void convert_weights(const float* __restrict__ Wih, const float* __restrict__ Whh,
                                const float* __restrict__ Wout,
                                unsigned short* __restrict__ wsA, unsigned short* __restrict__ wsO) {
    int gid = blockIdx.x * blockDim.x + threadIdx.x;
    if (gid < NMT * NKT * 64) {
        int lane = gid & 63, tile = gid >> 6;
        int kt = tile % NKT, mt = tile / NKT;
        int row = mt * 16 + (lane & 15);
        int kb  = kt * 32 + (lane >> 4) * 8;
        unsigned short o[8];
#pragma unroll
        for (int j = 0; j < 8; ++j) {
            int k = kb + j;
            float v = (k < EE) ? Wih[row * EE + k] : Whh[row * HH + (k - EE)];
            o[j] = f2bf(v);
        }
        uint4 pk;
        pk.x = o[0] | ((unsigned)o[1] << 16); pk.y = o[2] | ((unsigned)o[3] << 16);
        pk.z = o[4] | ((unsigned)o[5] << 16); pk.w = o[6] | ((unsigned)o[7] << 16);
        *(uint4*)(wsA + (size_t)gid * 8) = pk;
    } else {
        int g2 = gid - NMT * NKT * 64;
        if (g2 < NMT * NKT_O * 64) {
            int lane = g2 & 63, tile = g2 >> 6;
            int kt = tile % NKT_O, mt = tile / NKT_O;
            int row = mt * 16 + (lane & 15);
            int ub  = kt * 32 + (lane >> 4) * 8;
            unsigned short o[8];
#pragma unroll
            for (int j = 0; j < 8; ++j)
                o[j] = (row < LL) ? f2bf(Wout[row * HH + ub + j]) : (unsigned short)0;
            uint4 pk;
            pk.x = o[0] | ((unsigned)o[1] << 16); pk.y = o[2] | ((unsigned)o[3] << 16);
            pk.z = o[4] | ((unsigned)o[5] << 16); pk.w = o[6] | ((unsigned)o[7] << 16);
            *(uint4*)(wsO + (size_t)g2 * 8) = pk;
        }
    }
}

// 1 block = 32 seqs (2 col-groups), 8 waves. Each A-fragment fetched once per
// step feeds 2 MFMAs. nt-loads keep the emb gather stream out of L2 so wsA
// stays L2-resident (8 blocks/XCD -> 2.4 TB/s < per-XCD L2 BW).
__launch_bounds__(NT, 2)
__global__ void lstm_mfma_kernel(
    const int* __restrict__ tokens, const int* __restrict__ lengths,
    const int* __restrict__ labels, const float* __restrict__ emb,
    const float* __restrict__ bih,  const float* __restrict__ bhh,
    const float* __restrict__ bout,
    const unsigned short* __restrict__ wsA, const unsigned short* __restrict__ wsO,
    float* __restrict__ out)
{
    // B-fragment buffers: [buf][ (kt*2+cg)*64 + lane ][8]
    __shared__ unsigned short fr[2][NKT * 2 * 64 * 8];   // 2 x 24 KB
    __shared__ float bias_s[GG];                          // 4 KB
    __shared__ float redm[8][32];
    __shared__ float reds[8][32];
    __shared__ float labLogit[32];
    __shared__ int   labv[32];

    const int tid = threadIdx.x;
    const int w  = tid >> 6;        // wave 0..7
    const int l  = tid & 63;        // lane
    const int lq = l >> 4;          // row-group 0..3
    const int ls = l & 15;          // seq-in-colgroup 0..15
    const int n0 = blockIdx.x * BS;

    // lengths: per-lane for both col groups + block maxlen
    const int len_cg0 = lengths[n0 + ls];
    const int len_cg1 = lengths[n0 + 16 + ls];
    int maxlen = lengths[n0 + (l & 31)];
#pragma unroll
    for (int m = 1; m < 32; m <<= 1) maxlen = max(maxlen, __shfl_xor(maxlen, m, 64));

    if (tid < 32) labv[tid] = labels[n0 + tid];
    for (int i = tid; i < GG; i += NT) bias_s[i] = bih[i] + bhh[i];

    float c_reg[2][2][4], h_reg[2][2][4];   // [cg][jj][r]
#pragma unroll
    for (int cg = 0; cg < 2; ++cg)
#pragma unroll
        for (int jj = 0; jj < 2; ++jj)
#pragma unroll
            for (int r = 0; r < 4; ++r) { c_reg[cg][jj][r] = 0.0f; h_reg[cg][jj][r] = 0.0f; }

    // write this thread's h values for half-tile jj into fragment buffer
    auto writeH = [&](int buf, int jj) {
        const int k0   = EE + (2 * w + jj) * 16 + 4 * lq;     // k index of h unit
        const int kt   = k0 >> 5;
        const int lnp  = ls + 16 * ((k0 >> 3) & 3);
        const int joff = 4 * (lq & 1);
#pragma unroll
        for (int cg = 0; cg < 2; ++cg) {
            uint2 pk;
            pk.x = f2bf(h_reg[cg][jj][0]) | ((unsigned)f2bf(h_reg[cg][jj][1]) << 16);
            pk.y = f2bf(h_reg[cg][jj][2]) | ((unsigned)f2bf(h_reg[cg][jj][3]) << 16);
            *(uint2*)&fr[buf][(((kt * 2 + cg) * 64) + lnp) * 8 + joff] = pk;
        }
    };

    // x staging map: thread -> (seq, 8-wide k chunk)
    const int sseq = tid & 31;
    const int scg  = sseq >> 4;
    const int ssl  = sseq & 15;
    const int sk0  = (tid >> 5) * 8;    // 0..120
    const int slnp = ssl + 16 * ((sk0 >> 3) & 3);
    unsigned short* const sdst = &fr[0][0] + ((((sk0 >> 5) * 2 + scg) * 64) + slnp) * 8;
    const int frStride = NKT * 2 * 64 * 8;

    auto stageWrite = [&](int buf, f32x4 xa, f32x4 xb) {
        uint4 pk;
        pk.x = f2bf(xa[0]) | ((unsigned)f2bf(xa[1]) << 16);
        pk.y = f2bf(xa[2]) | ((unsigned)f2bf(xa[3]) << 16);
        pk.z = f2bf(xb[0]) | ((unsigned)f2bf(xb[1]) << 16);
        pk.w = f2bf(xb[2]) | ((unsigned)f2bf(xb[3]) << 16);
        *(uint4*)(sdst + buf * frStride) = pk;
    };

    // ---- prologue: h=0 frags + x[0] into buf 0 ----
    writeH(0, 0); writeH(0, 1);
    {
        int tok = __builtin_nontemporal_load(&tokens[(n0 + sseq) * TT + 0]);
        const float* er = emb + (size_t)tok * EE + sk0;
        f32x4 xa = __builtin_nontemporal_load((const f32x4*)er);
        f32x4 xb = __builtin_nontemporal_load((const f32x4*)(er + 4));
        stageWrite(0, xa, xb);
    }
    __syncthreads();

    // ---- recurrence ----
    for (int t = 0; t < maxlen; ++t) {
        const int cur = t & 1, nxt = cur ^ 1;
        const bool doStage = (t + 1 < maxlen);

        // B fragments for both col groups (LDS, contiguous, conflict-free)
        bf16x8 bq[2][NKT];
#pragma unroll
        for (int kt = 0; kt < NKT; ++kt) {
            bq[0][kt] = *(const bf16x8*)&fr[cur][((kt * 2 + 0) * 64 + l) * 8];
            bq[1][kt] = *(const bf16x8*)&fr[cur][((kt * 2 + 1) * 64 + l) * 8];
        }

        // prefetch next-step embedding (nt: don't pollute L2)
        f32x4 xa, xb;
        if (doStage) {
            int tok = __builtin_nontemporal_load(&tokens[(n0 + sseq) * TT + t + 1]);
            const float* er = emb + (size_t)tok * EE + sk0;
            xa = __builtin_nontemporal_load((const f32x4*)er);
            xb = __builtin_nontemporal_load((const f32x4*)(er + 4));
        }

#pragma unroll
        for (int jj = 0; jj < 2; ++jj) {
            f32x4 acc[4][2];   // [gate][cg]
#pragma unroll
            for (int g = 0; g < 4; ++g) {
                const int mt = g * 16 + 2 * w + jj;
                const f32x4 binit = *(const f32x4*)&bias_s[mt * 16 + 4 * lq];
                const bf16x8* ap = (const bf16x8*)wsA + (size_t)mt * (NKT * 64) + l;
                f32x4 a0 = binit, a1 = binit;
#pragma unroll
                for (int kt = 0; kt < NKT; ++kt) {
                    const bf16x8 af = ap[kt * 64];
                    a0 = __builtin_amdgcn_mfma_f32_16x16x32_bf16(af, bq[0][kt], a0, 0, 0, 0);
                    a1 = __builtin_amdgcn_mfma_f32_16x16x32_bf16(af, bq[1][kt], a1, 0, 0, 0);
                }
                acc[g][0] = a0; acc[g][1] = a1;
            }
            // cell update for this half-tile
#pragma unroll
            for (int cg = 0; cg < 2; ++cg) {
                const bool live = t < (cg ? len_cg1 : len_cg0);
#pragma unroll
                for (int r = 0; r < 4; ++r) {
                    if (live) {
                        float ig = sigf(acc[0][cg][r]);
                        float fg = sigf(acc[1][cg][r]);
                        float gg = tanh_fast(acc[2][cg][r]);
                        float og = sigf(acc[3][cg][r]);
                        float c  = fg * c_reg[cg][jj][r] + ig * gg;
                        c_reg[cg][jj][r] = c;
                        h_reg[cg][jj][r] = og * tanh_fast(c);
                    }
                }
            }
            writeH(nxt, jj);
        }

        if (doStage) stageWrite(nxt, xa, xb);
        __syncthreads();
    }

    // ---- epilogue 1: embeds = mean(c_f) ----
#pragma unroll
    for (int jj = 0; jj < 2; ++jj)
#pragma unroll
        for (int r = 0; r < 4; ++r) {
            float v = c_reg[0][jj][r] + c_reg[1][jj][r];
            v += __shfl_xor(v, 1, 64);
            v += __shfl_xor(v, 2, 64);
            v += __shfl_xor(v, 4, 64);
            v += __shfl_xor(v, 8, 64);
            if (ls == 0) {
                int u = (2 * w + jj) * 16 + 4 * lq + r;
                atomicAdd(&out[u], v * (1.0f / NSEQ));
            }
        }

    // ---- epilogue 2: logits GEMM + log-softmax ----
    const int fin = maxlen & 1;
    bf16x8 bq2[2][NKT_O];
#pragma unroll
    for (int kt = 0; kt < NKT_O; ++kt) {
        bq2[0][kt] = *(const bf16x8*)&fr[fin][(((4 + kt) * 2 + 0) * 64 + l) * 8];
        bq2[1][kt] = *(const bf16x8*)&fr[fin][(((4 + kt) * 2 + 1) * 64 + l) * 8];
    }

    float vals[8][2][4];
    float lmax0 = -INFINITY, lmax1 = -INFINITY;
#pragma unroll
    for (int i = 0; i < 8; ++i) {
        const int mt = 8 * w + i;
        const bf16x8* ap = (const bf16x8*)wsO + (size_t)mt * (NKT_O * 64) + l;
        f32x4 a0 = {0.0f, 0.0f, 0.0f, 0.0f}, a1 = a0;
#pragma unroll
        for (int kt = 0; kt < NKT_O; ++kt) {
            const bf16x8 af = ap[kt * 64];
            a0 = __builtin_amdgcn_mfma_f32_16x16x32_bf16(af, bq2[0][kt], a0, 0, 0, 0);
            a1 = __builtin_amdgcn_mfma_f32_16x16x32_bf16(af, bq2[1][kt], a1, 0, 0, 0);
        }
#pragma unroll
        for (int r = 0; r < 4; ++r) {
            int cls = mt * 16 + 4 * lq + r;
            float bo = (cls < LL) ? bout[cls] : 0.0f;
            float v0 = (cls < LL) ? (a0[r] + bo) : -INFINITY;
            float v1 = (cls < LL) ? (a1[r] + bo) : -INFINITY;
            vals[i][0][r] = v0; vals[i][1][r] = v1;
            lmax0 = fmaxf(lmax0, v0); lmax1 = fmaxf(lmax1, v1);
            if (cls == labv[ls])      labLogit[ls]      = v0;
            if (cls == labv[16 + ls]) labLogit[16 + ls] = v1;
        }
    }
    lmax0 = fmaxf(lmax0, __shfl_xor(lmax0, 16, 64));
    lmax0 = fmaxf(lmax0, __shfl_xor(lmax0, 32, 64));
    lmax1 = fmaxf(lmax1, __shfl_xor(lmax1, 16, 64));
    lmax1 = fmaxf(lmax1, __shfl_xor(lmax1, 32, 64));
    if (l < 16) { redm[w][ls] = lmax0; redm[w][16 + ls] = lmax1; }
    __syncthreads();

    float bm0 = redm[0][ls], bm1 = redm[0][16 + ls];
#pragma unroll
    for (int w2 = 1; w2 < 8; ++w2) {
        bm0 = fmaxf(bm0, redm[w2][ls]);
        bm1 = fmaxf(bm1, redm[w2][16 + ls]);
    }

    float s0 = 0.0f, s1 = 0.0f;
#pragma unroll
    for (int i = 0; i < 8; ++i)
#pragma unroll
        for (int r = 0; r < 4; ++r) {
            s0 += __expf(vals[i][0][r] - bm0);
            s1 += __expf(vals[i][1][r] - bm1);
        }
    s0 += __shfl_xor(s0, 16, 64);
    s0 += __shfl_xor(s0, 32, 64);
    s1 += __shfl_xor(s1, 16, 64);
    s1 += __shfl_xor(s1, 32, 64);
    if (l < 16) { reds[w][ls] = s0; reds[w][16 + ls] = s1; }
    __syncthreads();

    if (tid < 32) {
        float bm = redm[0][tid], tot = 0.0f;
#pragma unroll
        for (int w2 = 1; w2 < 8; ++w2) bm = fmaxf(bm, redm[w2][tid]);
#pragma unroll
        for (int w2 = 0; w2 < 8; ++w2) tot += reds[w2][tid];
        float lp = labLogit[tid] - bm - __logf(tot);
        atomicAdd(&out[HH], -lp * (1.0f / NSEQ));
    }
}

extern "C" void kernel_launch(void* const* d_in, const int* in_sizes, int n_in,
                              void* d_out, int out_size, void* d_ws, size_t ws_size,
                              hipStream_t stream)
{
    const int*   tokens  = (const int*)d_in[0];
    const int*   lengths = (const int*)d_in[1];
    const int*   labels  = (const int*)d_in[2];
    const float* emb     = (const float*)d_in[3];
    const float* Wih     = (const float*)d_in[4];
    const float* Whh     = (const float*)d_in[5];
    const float* bih     = (const float*)d_in[6];
    const float* bhh     = (const float*)d_in[7];
    const float* Wout    = (const float*)d_in[8];
    const float* bout    = (const float*)d_in[9];
    float* out = (float*)d_out;

    unsigned short* wsA = (unsigned short*)d_ws;
    unsigned short* wsO = wsA + WSA_ELEMS;

    hipLaunchKernelGGL(init_out_kernel, dim3(2), dim3(256), 0, stream, out);
    {
        int nthr = NMT * NKT * 64 + NMT * NKT_O * 64;
        hipLaunchKernelGGL(convert_weights, dim3((nthr + 255) / 256), dim3(256), 0, stream,
                           Wih, Whh, Wout, wsA, wsO);
    }
    hipLaunchKernelGGL(lstm_mfma_kernel, dim3(NBLK), dim3(NT), 0, stream,
                       tokens, lengths, labels, emb, bih, bhh, bout, wsA, wsO, out);
}

// Round 4
// 3764.014 us; speedup vs baseline: 1.0145x; 1.0145x over previous
//
#include <hip/hip_runtime.h>
#include <hip/hip_bf16.h>
#include <math.h>

// Problem constants
#define NSEQ 2048
#define TT   128
#define EE   128
#define HH   256
#define GG   1024      // 4*H gate rows
#define LL   1000
#define NT   512       // threads per block (8 waves)
#define NPAIR 128      // pairs of blocks; pair handles 16 seqs
#define NBLK  256      // 2 blocks per pair, 1 block per CU
#define NKT  12        // K tiles of 32: 4 (x) + 8 (h)
#define NMT  64        // M tiles of 16: 1024 gate rows
#define NKT_O 8        // K tiles for output GEMM (H=256)
#define WSA_ELEMS (NMT * NKT * 64 * 8)      // 768 KB bf16
#define WSO_ELEMS (NMT * NKT_O * 64 * 8)    // 512 KB bf16
#define HBUF_SHORTS 2048                     // one slot: 4 kt * 64 lanes * 8 = 4 KB
#define HBUF_ELEMS (NPAIR * 2 * 2 * HBUF_SHORTS)   // pairs x q x parity = 2 MB

typedef __attribute__((ext_vector_type(8))) short bf16x8;
typedef __attribute__((ext_vector_type(4))) float f32x4;

__device__ __forceinline__ unsigned short f2bf(float f) {
    union { float f; unsigned u; } v; v.f = f;
    unsigned r = v.u + 0x7FFF + ((v.u >> 16) & 1);   // RNE
    return (unsigned short)(r >> 16);
}
__device__ __forceinline__ float sigf(float x) { return 1.0f / (1.0f + __expf(-x)); }
__device__ __forceinline__ float tanh_fast(float x) { return 1.0f - 2.0f / (1.0f + __expf(2.0f * x)); }

__global__ void init_out_kernel(float* out, int* flags) {
    int i = blockIdx.x * blockDim.x + threadIdx.x;
    if (i < HH + 1) out[i] = 0.0f;
    if (i < 2 * NPAIR) flags[i] = 0;
}

// Pre-shuffle weights into MFMA A-fragment order, bf16 (layout as R2/R3 - verified).
__global__ void convert_weights(const float* __restrict__ Wih, const float* __restrict__ Whh,
                                const float* __restrict__ Wout,
                                unsigned short* __restrict__ wsA, unsigned short* __restrict__ wsO) {
    int gid = blockIdx.x * blockDim.x + threadIdx.x;
    if (gid < NMT * NKT * 64) {
        int lane = gid & 63, tile = gid >> 6;
        int kt = tile % NKT, mt = tile / NKT;
        int row = mt * 16 + (lane & 15);
        int kb  = kt * 32 + (lane >> 4) * 8;
        unsigned short o[8];
#pragma unroll
        for (int j = 0; j < 8; ++j) {
            int k = kb + j;
            float v = (k < EE) ? Wih[row * EE + k] : Whh[row * HH + (k - EE)];
            o[j] = f2bf(v);
        }
        uint4 pk;
        pk.x = o[0] | ((unsigned)o[1] << 16); pk.y = o[2] | ((unsigned)o[3] << 16);
        pk.z = o[4] | ((unsigned)o[5] << 16); pk.w = o[6] | ((unsigned)o[7] << 16);
        *(uint4*)(wsA + (size_t)gid * 8) = pk;
    } else {
        int g2 = gid - NMT * NKT * 64;
        if (g2 < NMT * NKT_O * 64) {
            int lane = g2 & 63, tile = g2 >> 6;
            int kt = tile % NKT_O, mt = tile / NKT_O;
            int row = mt * 16 + (lane & 15);
            int ub  = kt * 32 + (lane >> 4) * 8;
            unsigned short o[8];
#pragma unroll
            for (int j = 0; j < 8; ++j)
                o[j] = (row < LL) ? f2bf(Wout[row * HH + ub + j]) : (unsigned short)0;
            uint4 pk;
            pk.x = o[0] | ((unsigned)o[1] << 16); pk.y = o[2] | ((unsigned)o[3] << 16);
            pk.z = o[4] | ((unsigned)o[5] << 16); pk.w = o[6] | ((unsigned)o[7] << 16);
            *(uint4*)(wsO + (size_t)g2 * 8) = pk;
        }
    }
}

// Pair-split LSTM: 2 blocks per 16 seqs. Block q owns units [128q,128q+128):
// W_hh slice persistent in VGPRs (128/wave), W_ih slice in LDS (128 KB).
// Per step: MFMA gates (x + own-h while partner's half-h arrives via L2 flags),
// in-register cell update (i,f,g,o aligned per wave), publish half-h.
__launch_bounds__(NT, 2)
__global__ void lstm_pair_kernel(
    const int* __restrict__ tokens, const int* __restrict__ lengths,
    const int* __restrict__ labels, const float* __restrict__ emb,
    const float* __restrict__ bih,  const float* __restrict__ bhh,
    const float* __restrict__ bout,
    const unsigned short* __restrict__ wsA, const unsigned short* __restrict__ wsO,
    unsigned short* __restrict__ hbuf, int* __restrict__ flags,
    float* __restrict__ out)
{
    __shared__ unsigned short wih[32 * 4 * 64 * 8];   // 128 KB: W_ih A-frags (32 mt x 4 kt)
    __shared__ unsigned short xf[4 * 64 * 8];          // 4 KB: x B-frags
    __shared__ unsigned short hf[4 * 64 * 8];          // 4 KB: own-half h B-frags
    __shared__ float redm[8][16];
    __shared__ float reds[8][16];
    __shared__ float labLogit[16];
    __shared__ int   labv[16];

    const int tid = threadIdx.x;
    const int w  = tid >> 6;        // wave 0..7
    const int l  = tid & 63;
    const int lq = l >> 4;          // row-group 0..3
    const int ls = l & 15;          // seq 0..15
    const int pair = blockIdx.x & (NPAIR - 1);
    const int q    = blockIdx.x >> 7;   // 0 or 1 (blocks b and b+128 pair; same XCD under %8 round-robin)
    const int n0   = pair * 16;

    int* const myF = &flags[2 * pair + q];
    const int* const prF = &flags[2 * pair + (q ^ 1)];
    unsigned short* const gbMy0 = hbuf + ((size_t)(pair * 2 + q) * 2 + 0) * HBUF_SHORTS;
    unsigned short* const gbMy1 = gbMy0 + HBUF_SHORTS;
    const unsigned short* const gbPr0 = hbuf + ((size_t)(pair * 2 + (q ^ 1)) * 2 + 0) * HBUF_SHORTS;
    const unsigned short* const gbPr1 = gbPr0 + HBUF_SHORTS;

    const int len_s = lengths[n0 + ls];
    int maxlen = len_s;
#pragma unroll
    for (int m = 1; m < 16; m <<= 1) maxlen = max(maxlen, __shfl_xor(maxlen, m, 64));

    if (tid < 16) labv[tid] = labels[n0 + tid];

    // ---- persistent weights: W_hh slice in registers (128 VGPR/wave) ----
    bf16x8 whh[4][8];
    f32x4  biasv[4];
#pragma unroll
    for (int g = 0; g < 4; ++g) {
        const int mt = g * 16 + 8 * q + w;
        const bf16x8* ap = (const bf16x8*)wsA + (size_t)mt * (NKT * 64) + l;
#pragma unroll
        for (int kk = 0; kk < 8; ++kk) whh[g][kk] = ap[(4 + kk) * 64];
#pragma unroll
        for (int r = 0; r < 4; ++r) {
            int row = mt * 16 + 4 * lq + r;
            biasv[g][r] = bih[row] + bhh[row];
        }
    }

    // ---- W_ih slice -> LDS (one-time) ----
    for (int idx = tid; idx < 32 * 4 * 64; idx += NT) {
        int mtl = idx >> 8, kt = (idx >> 6) & 3, l2 = idx & 63;
        int g = mtl >> 3, w2 = mtl & 7;
        int mt = g * 16 + 8 * q + w2;
        *(uint4*)&wih[(size_t)idx * 8] =
            *(const uint4*)(wsA + (((size_t)mt * NKT + kt) * 64 + l2) * 8);
    }

    // zero own h frags (LDS + global buf parity 0)
    {
        uint2 z; z.x = 0; z.y = 0;
        ((uint2*)hf)[tid] = z;
        ((uint2*)gbMy0)[tid] = z;
    }

    // x staging map: thread -> (seq, 4-wide k chunk)
    const int sseq  = tid & 15;
    const int chunk = tid >> 4;          // 0..31
    const int sk0   = chunk * 4;
    unsigned short* const sdst = &xf[(((chunk >> 3) * 64) + sseq + 16 * ((chunk >> 1) & 3)) * 8 + (chunk & 1) * 4];

    // stage x(0)
    {
        int tok = __builtin_nontemporal_load(&tokens[(n0 + sseq) * TT + 0]);
        f32x4 xv = __builtin_nontemporal_load((const f32x4*)(emb + (size_t)tok * EE + sk0));
        uint2 pk;
        pk.x = f2bf(xv[0]) | ((unsigned)f2bf(xv[1]) << 16);
        pk.y = f2bf(xv[2]) | ((unsigned)f2bf(xv[3]) << 16);
        *(uint2*)sdst = pk;
    }
    __syncthreads();   // drains LDS + vmem stores
    if (tid == 0) __hip_atomic_fetch_add(myF, 1, __ATOMIC_RELEASE, __HIP_MEMORY_SCOPE_AGENT);  // h(0) published

    float c_reg[4], h_reg[4];
#pragma unroll
    for (int r = 0; r < 4; ++r) { c_reg[r] = 0.0f; h_reg[r] = 0.0f; }

    // h-frag write mapping (unit k = 128q + 16w + 4lq + r)
    const int ktOwn = w >> 1;
    const int lanep = ls + 16 * ((2 * w + (lq >> 1)) & 3);
    const int j0    = 4 * (lq & 1);
    const int hoff  = (ktOwn * 64 + lanep) * 8 + j0;

    // ---- recurrence ----
    for (int t = 0; t < maxlen; ++t) {
        // read own B-frags (before barrier1)
        bf16x8 bx[4], bo[4];
#pragma unroll
        for (int k = 0; k < 4; ++k) bx[k] = *(const bf16x8*)&xf[(k * 64 + l) * 8];
#pragma unroll
        for (int k = 0; k < 4; ++k) bo[k] = *(const bf16x8*)&hf[(k * 64 + l) * 8];

        // prefetch x(t+1)
        const bool doX = (t + 1 < maxlen);
        f32x4 xv;
        if (doX) {
            int tok = __builtin_nontemporal_load(&tokens[(n0 + sseq) * TT + t + 1]);
            xv = __builtin_nontemporal_load((const f32x4*)(emb + (size_t)tok * EE + sk0));
        }

        __syncthreads();   // barrier1: all LDS reads done; writes may begin after

        f32x4 acc[4];
#pragma unroll
        for (int g = 0; g < 4; ++g) acc[g] = biasv[g];

        // x-part (A from LDS) — overlaps with partner's publish latency
#pragma unroll
        for (int kt = 0; kt < 4; ++kt) {
#pragma unroll
            for (int g = 0; g < 4; ++g) {
                const bf16x8 af = *(const bf16x8*)&wih[(((g * 8 + w) * 4 + kt) * 64 + l) * 8];
                acc[g] = __builtin_amdgcn_mfma_f32_16x16x32_bf16(af, bx[kt], acc[g], 0, 0, 0);
            }
        }
        // own-h part (A from registers)
#pragma unroll
        for (int ko = 0; ko < 4; ++ko) {
#pragma unroll
            for (int g = 0; g < 4; ++g)
                acc[g] = __builtin_amdgcn_mfma_f32_16x16x32_bf16(whh[g][4 * q + ko], bo[ko], acc[g], 0, 0, 0);
        }

        // wait for partner h(t), acquire (per-wave: invalidates caches)
        while (__hip_atomic_load(prF, __ATOMIC_ACQUIRE, __HIP_MEMORY_SCOPE_AGENT) < t + 1)
            __builtin_amdgcn_s_sleep(2);
        {
            const unsigned short* gp = (t & 1) ? gbPr1 : gbPr0;
#pragma unroll
            for (int ko = 0; ko < 4; ++ko) {
                const bf16x8 bp = *(const bf16x8*)&gp[(ko * 64 + l) * 8];
#pragma unroll
                for (int g = 0; g < 4; ++g)
                    acc[g] = __builtin_amdgcn_mfma_f32_16x16x32_bf16(whh[g][4 * (q ^ 1) + ko], bp, acc[g], 0, 0, 0);
            }
        }

        // in-register cell update (i,f,g,o aligned per wave)
        const bool live = (t < len_s);
#pragma unroll
        for (int r = 0; r < 4; ++r) {
            if (live) {
                float ig = sigf(acc[0][r]);
                float fg = sigf(acc[1][r]);
                float gg = tanh_fast(acc[2][r]);
                float og = sigf(acc[3][r]);
                float cc = fg * c_reg[r] + ig * gg;
                c_reg[r] = cc;
                h_reg[r] = og * tanh_fast(cc);
            }
        }

        // publish h(t+1): LDS (own reuse) + global (partner), parity (t+1)&1
        {
            uint2 hp;
            hp.x = f2bf(h_reg[0]) | ((unsigned)f2bf(h_reg[1]) << 16);
            hp.y = f2bf(h_reg[2]) | ((unsigned)f2bf(h_reg[3]) << 16);
            *(uint2*)&hf[hoff] = hp;
            unsigned short* gm = ((t + 1) & 1) ? gbMy1 : gbMy0;
            *(uint2*)&gm[hoff] = hp;
        }
        if (doX) {
            uint2 pk;
            pk.x = f2bf(xv[0]) | ((unsigned)f2bf(xv[1]) << 16);
            pk.y = f2bf(xv[2]) | ((unsigned)f2bf(xv[3]) << 16);
            *(uint2*)sdst = pk;
        }

        __syncthreads();   // barrier2: compiler drains vmcnt+lgkmcnt before s_barrier
        if (tid == 0) __hip_atomic_fetch_add(myF, 1, __ATOMIC_RELEASE, __HIP_MEMORY_SCOPE_AGENT); // flag = t+2
    }

    // ---- epilogue 1: embeds (own 128 units) ----
#pragma unroll
    for (int r = 0; r < 4; ++r) {
        float v = c_reg[r];
        v += __shfl_xor(v, 1, 64);
        v += __shfl_xor(v, 2, 64);
        v += __shfl_xor(v, 4, 64);
        v += __shfl_xor(v, 8, 64);
        if (ls == 0) {
            int u = 128 * q + 16 * w + 4 * lq + r;
            atomicAdd(&out[u], v * (1.0f / NSEQ));
        }
    }

    // ---- epilogue 2 (q==0 only): logits GEMM + log-softmax ----
    if (q == 0) {
        while (__hip_atomic_load(prF, __ATOMIC_ACQUIRE, __HIP_MEMORY_SCOPE_AGENT) < maxlen + 1)
            __builtin_amdgcn_s_sleep(2);

        bf16x8 bq2[8];
#pragma unroll
        for (int ko = 0; ko < 4; ++ko) bq2[ko] = *(const bf16x8*)&hf[(ko * 64 + l) * 8];
        {
            const unsigned short* gp = (maxlen & 1) ? gbPr1 : gbPr0;
#pragma unroll
            for (int ko = 0; ko < 4; ++ko) bq2[4 + ko] = *(const bf16x8*)&gp[(ko * 64 + l) * 8];
        }

        float vals[8][4];
        float lmax = -INFINITY;
#pragma unroll
        for (int i = 0; i < 8; ++i) {
            const int mt = 8 * w + i;
            const bf16x8* ap = (const bf16x8*)wsO + (size_t)mt * (NKT_O * 64) + l;
            f32x4 a = {0.0f, 0.0f, 0.0f, 0.0f};
#pragma unroll
            for (int kt = 0; kt < NKT_O; ++kt)
                a = __builtin_amdgcn_mfma_f32_16x16x32_bf16(ap[kt * 64], bq2[kt], a, 0, 0, 0);
#pragma unroll
            for (int r = 0; r < 4; ++r) {
                int cls = mt * 16 + 4 * lq + r;
                float v = (cls < LL) ? (a[r] + bout[cls]) : -INFINITY;
                vals[i][r] = v;
                lmax = fmaxf(lmax, v);
                if (cls == labv[ls]) labLogit[ls] = v;
            }
        }
        lmax = fmaxf(lmax, __shfl_xor(lmax, 16, 64));
        lmax = fmaxf(lmax, __shfl_xor(lmax, 32, 64));
        if (l < 16) redm[w][l] = lmax;
        __syncthreads();

        float bm = redm[0][ls];
#pragma unroll
        for (int w2 = 1; w2 < 8; ++w2) bm = fmaxf(bm, redm[w2][ls]);

        float s = 0.0f;
#pragma unroll
        for (int i = 0; i < 8; ++i)
#pragma unroll
            for (int r = 0; r < 4; ++r) s += __expf(vals[i][r] - bm);
        s += __shfl_xor(s, 16, 64);
        s += __shfl_xor(s, 32, 64);
        if (l < 16) reds[w][l] = s;
        __syncthreads();

        if (tid < 16) {
            float bm2 = redm[0][tid], tot = 0.0f;
#pragma unroll
            for (int w2 = 1; w2 < 8; ++w2) bm2 = fmaxf(bm2, redm[w2][tid]);
#pragma unroll
            for (int w2 = 0; w2 < 8; ++w2) tot += reds[w2][tid];
            float lp = labLogit[tid] - bm2 - __logf(tot);
            atomicAdd(&out[HH], -lp * (1.0f / NSEQ));
        }
    }
}

extern "C" void kernel_launch(void* const* d_in, const int* in_sizes, int n_in,
                              void* d_out, int out_size, void* d_ws, size_t ws_size,
                              hipStream_t stream)
{
    const int*   tokens  = (const int*)d_in[0];
    const int*   lengths = (const int*)d_in[1];
    const int*   labels  = (const int*)d_in[2];
    const float* emb     = (const float*)d_in[3];
    const float* Wih     = (const float*)d_in[4];
    const float* Whh     = (const float*)d_in[5];
    const float* bih     = (const float*)d_in[6];
    const float* bhh     = (const float*)d_in[7];
    const float* Wout    = (const float*)d_in[8];
    const float* bout    = (const float*)d_in[9];
    float* out = (float*)d_out;

    unsigned short* wsA  = (unsigned short*)d_ws;
    unsigned short* wsO  = wsA + WSA_ELEMS;
    unsigned short* hbuf = wsO + WSO_ELEMS;
    int*            flg  = (int*)(hbuf + HBUF_ELEMS);   // 256 ints; total ws ~3.3 MB

    hipLaunchKernelGGL(init_out_kernel, dim3(1), dim3(512), 0, stream, out, flg);
    {
        int nthr = NMT * NKT * 64 + NMT * NKT_O * 64;
        hipLaunchKernelGGL(convert_weights, dim3((nthr + 255) / 256), dim3(256), 0, stream,
                           Wih, Whh, Wout, wsA, wsO);
    }
    hipLaunchKernelGGL(lstm_pair_kernel, dim3(NBLK), dim3(NT), 0, stream,
                       tokens, lengths, labels, emb, bih, bhh, bout, wsA, wsO, hbuf, flg, out);
}

// Round 5
// 3651.476 us; speedup vs baseline: 1.0458x; 1.0308x over previous
//
#include <hip/hip_runtime.h>
#include <hip/hip_bf16.h>
#include <math.h>

// Problem constants
#define NSEQ 2048
#define TT   128
#define EE   128
#define HH   256
#define GG   1024      // 4*H gate rows
#define LL   1000
#define NT   512       // threads per block (8 waves)
#define NPAIR 128      // pairs of blocks; pair handles 16 seqs
#define NBLK  256      // 2 blocks per pair, 1 block per CU
#define NKT  12        // K tiles of 32: 4 (x) + 8 (h)
#define NMT  64        // M tiles of 16: 1024 gate rows
#define NKT_O 8        // K tiles for output GEMM (H=256)
#define WSA_ELEMS (NMT * NKT * 64 * 8)      // 768 KB bf16
#define WSO_ELEMS (NMT * NKT_O * 64 * 8)    // 512 KB bf16
#define HBUF_SHORTS 2048                     // one slot: 4 kt * 64 lanes * 8 = 4 KB
#define HBUF_ELEMS (NPAIR * 2 * 2 * HBUF_SHORTS)   // pairs x q x parity = 2 MB

typedef __attribute__((ext_vector_type(8))) short bf16x8;
typedef __attribute__((ext_vector_type(4))) float f32x4;

typedef union { bf16x8 v; float f[4]; } fragu;

__device__ __forceinline__ unsigned short f2bf(float f) {
    union { float f; unsigned u; } v; v.f = f;
    unsigned r = v.u + 0x7FFF + ((v.u >> 16) & 1);   // RNE
    return (unsigned short)(r >> 16);
}
__device__ __forceinline__ float sigf(float x) { return 1.0f / (1.0f + __expf(-x)); }
__device__ __forceinline__ float tanh_fast(float x) { return 1.0f - 2.0f / (1.0f + __expf(2.0f * x)); }

__global__ void init_out_kernel(float* out, int* flags) {
    int i = blockIdx.x * blockDim.x + threadIdx.x;
    if (i < HH + 1) out[i] = 0.0f;
    if (i < 2 * NPAIR) flags[i] = 0;
}

// Pre-shuffle weights into MFMA A-fragment order, bf16 (layout verified R2-R4).
__global__ void convert_weights(const float* __restrict__ Wih, const float* __restrict__ Whh,
                                const float* __restrict__ Wout,
                                unsigned short* __restrict__ wsA, unsigned short* __restrict__ wsO) {
    int gid = blockIdx.x * blockDim.x + threadIdx.x;
    if (gid < NMT * NKT * 64) {
        int lane = gid & 63, tile = gid >> 6;
        int kt = tile % NKT, mt = tile / NKT;
        int row = mt * 16 + (lane & 15);
        int kb  = kt * 32 + (lane >> 4) * 8;
        unsigned short o[8];
#pragma unroll
        for (int j = 0; j < 8; ++j) {
            int k = kb + j;
            float v = (k < EE) ? Wih[row * EE + k] : Whh[row * HH + (k - EE)];
            o[j] = f2bf(v);
        }
        uint4 pk;
        pk.x = o[0] | ((unsigned)o[1] << 16); pk.y = o[2] | ((unsigned)o[3] << 16);
        pk.z = o[4] | ((unsigned)o[5] << 16); pk.w = o[6] | ((unsigned)o[7] << 16);
        *(uint4*)(wsA + (size_t)gid * 8) = pk;
    } else {
        int g2 = gid - NMT * NKT * 64;
        if (g2 < NMT * NKT_O * 64) {
            int lane = g2 & 63, tile = g2 >> 6;
            int kt = tile % NKT_O, mt = tile / NKT_O;
            int row = mt * 16 + (lane & 15);
            int ub  = kt * 32 + (lane >> 4) * 8;
            unsigned short o[8];
#pragma unroll
            for (int j = 0; j < 8; ++j)
                o[j] = (row < LL) ? f2bf(Wout[row * HH + ub + j]) : (unsigned short)0;
            uint4 pk;
            pk.x = o[0] | ((unsigned)o[1] << 16); pk.y = o[2] | ((unsigned)o[3] << 16);
            pk.z = o[4] | ((unsigned)o[5] << 16); pk.w = o[6] | ((unsigned)o[7] << 16);
            *(uint4*)(wsO + (size_t)g2 * 8) = pk;
        }
    }
}

// Pair-split LSTM: 2 blocks per 16 seqs. Block q owns units [128q,128q+128):
// W_hh slice PINNED in VGPRs via asm barriers (128/wave), W_ih slice in LDS.
__launch_bounds__(NT, 2)
__global__ void lstm_pair_kernel(
    const int* __restrict__ tokens, const int* __restrict__ lengths,
    const int* __restrict__ labels, const float* __restrict__ emb,
    const float* __restrict__ bih,  const float* __restrict__ bhh,
    const float* __restrict__ bout,
    const unsigned short* __restrict__ wsA, const unsigned short* __restrict__ wsO,
    unsigned short* __restrict__ hbuf, int* __restrict__ flags,
    float* __restrict__ out)
{
    __shared__ unsigned short wih[32 * 4 * 64 * 8];   // 128 KB: W_ih A-frags (32 mt x 4 kt)
    __shared__ unsigned short xf[4 * 64 * 8];          // 4 KB: x B-frags
    __shared__ unsigned short hf[4 * 64 * 8];          // 4 KB: own-half h B-frags
    __shared__ float bias_s[512];                      // 2 KB: this block's gate biases
    __shared__ float redm[8][16];
    __shared__ float reds[8][16];
    __shared__ float labLogit[16];
    __shared__ int   labv[16];

    const int tid = threadIdx.x;
    const int w  = tid >> 6;        // wave 0..7
    const int l  = tid & 63;
    const int lq = l >> 4;          // row-group 0..3
    const int ls = l & 15;          // seq 0..15
    const int pair = blockIdx.x & (NPAIR - 1);
    const int q    = blockIdx.x >> 7;   // 0/1: blocks b, b+128 pair (same XCD under %8)
    const int n0   = pair * 16;

    int* const myF = &flags[2 * pair + q];
    int* const prF = &flags[2 * pair + (q ^ 1)];
    unsigned short* const gbMy0 = hbuf + ((size_t)(pair * 2 + q) * 2 + 0) * HBUF_SHORTS;
    unsigned short* const gbMy1 = gbMy0 + HBUF_SHORTS;
    const unsigned short* const gbPr0 = hbuf + ((size_t)(pair * 2 + (q ^ 1)) * 2 + 0) * HBUF_SHORTS;
    const unsigned short* const gbPr1 = gbPr0 + HBUF_SHORTS;

    const int len_s = lengths[n0 + ls];
    int maxlen = len_s;
#pragma unroll
    for (int m = 1; m < 16; m <<= 1) maxlen = max(maxlen, __shfl_xor(maxlen, m, 64));

    if (tid < 16) labv[tid] = labels[n0 + tid];

    // ---- biases -> LDS (free 16 VGPRs vs register copy) ----
    if (tid < 512) {
        int g = tid >> 7, w2 = (tid >> 4) & 7, r16 = tid & 15;
        int row = (g * 16 + 8 * q + w2) * 16 + r16;
        bias_s[tid] = bih[row] + bhh[row];
    }

    // ---- persistent W_hh slice: 32 frags = 128 VGPR/wave, PINNED ----
    fragu whh[4][8];
#pragma unroll
    for (int g = 0; g < 4; ++g) {
        const int mt = g * 16 + 8 * q + w;
        const bf16x8* ap = (const bf16x8*)wsA + (size_t)mt * (NKT * 64) + l;
#pragma unroll
        for (int kk = 0; kk < 8; ++kk) whh[g][kk].v = ap[(4 + kk) * 64];
    }
    // opaque asm barrier: values can no longer be rematerialized from memory
#pragma unroll
    for (int g = 0; g < 4; ++g)
#pragma unroll
        for (int kk = 0; kk < 8; ++kk)
            asm volatile("" : "+v"(whh[g][kk].f[0]), "+v"(whh[g][kk].f[1]),
                              "+v"(whh[g][kk].f[2]), "+v"(whh[g][kk].f[3]));

    // ---- W_ih slice -> LDS (one-time) ----
    for (int idx = tid; idx < 32 * 4 * 64; idx += NT) {
        int mtl = idx >> 8, kt = (idx >> 6) & 3, l2 = idx & 63;
        int g = mtl >> 3, w2 = mtl & 7;
        int mt = g * 16 + 8 * q + w2;
        *(uint4*)&wih[(size_t)idx * 8] =
            *(const uint4*)(wsA + (((size_t)mt * NKT + kt) * 64 + l2) * 8);
    }

    // zero own h frags (LDS + global buf parity 0)
    {
        uint2 z; z.x = 0; z.y = 0;
        ((uint2*)hf)[tid] = z;
        ((uint2*)gbMy0)[tid] = z;
    }

    // x staging map: thread -> (seq, 4-wide k chunk)
    const int sseq  = tid & 15;
    const int chunk = tid >> 4;          // 0..31
    const int sk0   = chunk * 4;
    unsigned short* const sdst = &xf[(((chunk >> 3) * 64) + sseq + 16 * ((chunk >> 1) & 3)) * 8 + (chunk & 1) * 4];

    // stage x(0)
    {
        int tok = __builtin_nontemporal_load(&tokens[(n0 + sseq) * TT + 0]);
        f32x4 xv = __builtin_nontemporal_load((const f32x4*)(emb + (size_t)tok * EE + sk0));
        uint2 pk;
        pk.x = f2bf(xv[0]) | ((unsigned)f2bf(xv[1]) << 16);
        pk.y = f2bf(xv[2]) | ((unsigned)f2bf(xv[3]) << 16);
        *(uint2*)sdst = pk;
    }
    __syncthreads();   // drains LDS + vmem stores
    if (tid == 0) __hip_atomic_fetch_add(myF, 1, __ATOMIC_RELEASE, __HIP_MEMORY_SCOPE_AGENT);  // h(0) published

    float c_reg[4], h_reg[4];
#pragma unroll
    for (int r = 0; r < 4; ++r) { c_reg[r] = 0.0f; h_reg[r] = 0.0f; }

    // h-frag write mapping (unit k = 128q + 16w + 4lq + r)
    const int ktOwn = w >> 1;
    const int lanep = ls + 16 * ((2 * w + (lq >> 1)) & 3);
    const int j0    = 4 * (lq & 1);
    const int hoff  = (ktOwn * 64 + lanep) * 8 + j0;

    // ---- recurrence ----
    for (int t = 0; t < maxlen; ++t) {
        // read own B-frags (before barrier1)
        bf16x8 bx[4], bo[4];
#pragma unroll
        for (int k = 0; k < 4; ++k) bx[k] = *(const bf16x8*)&xf[(k * 64 + l) * 8];
#pragma unroll
        for (int k = 0; k < 4; ++k) bo[k] = *(const bf16x8*)&hf[(k * 64 + l) * 8];

        // prefetch x(t+1)
        const bool doX = (t + 1 < maxlen);
        f32x4 xv;
        if (doX) {
            int tok = __builtin_nontemporal_load(&tokens[(n0 + sseq) * TT + t + 1]);
            xv = __builtin_nontemporal_load((const f32x4*)(emb + (size_t)tok * EE + sk0));
        }

        __syncthreads();   // barrier1: all LDS reads done; writes may begin after

        f32x4 acc[4];
#pragma unroll
        for (int g = 0; g < 4; ++g) acc[g] = *(const f32x4*)&bias_s[(g * 8 + w) * 16 + 4 * lq];

        // x-part (A from LDS) — overlaps partner publish latency
#pragma unroll
        for (int kt = 0; kt < 4; ++kt) {
#pragma unroll
            for (int g = 0; g < 4; ++g) {
                const bf16x8 af = *(const bf16x8*)&wih[(((g * 8 + w) * 4 + kt) * 64 + l) * 8];
                acc[g] = __builtin_amdgcn_mfma_f32_16x16x32_bf16(af, bx[kt], acc[g], 0, 0, 0);
            }
        }
        // own-h part (A pinned in registers)
#pragma unroll
        for (int ko = 0; ko < 4; ++ko) {
#pragma unroll
            for (int g = 0; g < 4; ++g)
                acc[g] = __builtin_amdgcn_mfma_f32_16x16x32_bf16(whh[g][4 * q + ko].v, bo[ko], acc[g], 0, 0, 0);
        }

        // wait for partner h(t): relaxed spin, one acquire on exit
        while (__hip_atomic_load(prF, __ATOMIC_RELAXED, __HIP_MEMORY_SCOPE_AGENT) < t + 1)
            __builtin_amdgcn_s_sleep(2);
        (void)__hip_atomic_load(prF, __ATOMIC_ACQUIRE, __HIP_MEMORY_SCOPE_AGENT);
        {
            const unsigned short* gp = (t & 1) ? gbPr1 : gbPr0;
#pragma unroll
            for (int ko = 0; ko < 4; ++ko) {
                const bf16x8 bp = *(const bf16x8*)&gp[(ko * 64 + l) * 8];
#pragma unroll
                for (int g = 0; g < 4; ++g)
                    acc[g] = __builtin_amdgcn_mfma_f32_16x16x32_bf16(whh[g][4 * (q ^ 1) + ko].v, bp, acc[g], 0, 0, 0);
            }
        }

        // in-register cell update (i,f,g,o aligned per wave)
        const bool live = (t < len_s);
#pragma unroll
        for (int r = 0; r < 4; ++r) {
            if (live) {
                float ig = sigf(acc[0][r]);
                float fg = sigf(acc[1][r]);
                float gg = tanh_fast(acc[2][r]);
                float og = sigf(acc[3][r]);
                float cc = fg * c_reg[r] + ig * gg;
                c_reg[r] = cc;
                h_reg[r] = og * tanh_fast(cc);
            }
        }

        // publish h(t+1): LDS (own reuse) + global (partner), parity (t+1)&1
        {
            uint2 hp;
            hp.x = f2bf(h_reg[0]) | ((unsigned)f2bf(h_reg[1]) << 16);
            hp.y = f2bf(h_reg[2]) | ((unsigned)f2bf(h_reg[3]) << 16);
            *(uint2*)&hf[hoff] = hp;
            unsigned short* gm = ((t + 1) & 1) ? gbMy1 : gbMy0;
            *(uint2*)&gm[hoff] = hp;
        }
        if (doX) {
            uint2 pk;
            pk.x = f2bf(xv[0]) | ((unsigned)f2bf(xv[1]) << 16);
            pk.y = f2bf(xv[2]) | ((unsigned)f2bf(xv[3]) << 16);
            *(uint2*)sdst = pk;
        }

        __syncthreads();   // barrier2: drains vmcnt+lgkmcnt before s_barrier
        if (tid == 0) __hip_atomic_fetch_add(myF, 1, __ATOMIC_RELEASE, __HIP_MEMORY_SCOPE_AGENT); // flag = t+2
    }

    // ---- epilogue 1: embeds (own 128 units) ----
#pragma unroll
    for (int r = 0; r < 4; ++r) {
        float v = c_reg[r];
        v += __shfl_xor(v, 1, 64);
        v += __shfl_xor(v, 2, 64);
        v += __shfl_xor(v, 4, 64);
        v += __shfl_xor(v, 8, 64);
        if (ls == 0) {
            int u = 128 * q + 16 * w + 4 * lq + r;
            atomicAdd(&out[u], v * (1.0f / NSEQ));
        }
    }

    // ---- epilogue 2 (q==0 only): logits GEMM + log-softmax ----
    if (q == 0) {
        while (__hip_atomic_load(prF, __ATOMIC_RELAXED, __HIP_MEMORY_SCOPE_AGENT) < maxlen + 1)
            __builtin_amdgcn_s_sleep(2);
        (void)__hip_atomic_load(prF, __ATOMIC_ACQUIRE, __HIP_MEMORY_SCOPE_AGENT);

        bf16x8 bq2[8];
#pragma unroll
        for (int ko = 0; ko < 4; ++ko) bq2[ko] = *(const bf16x8*)&hf[(ko * 64 + l) * 8];
        {
            const unsigned short* gp = (maxlen & 1) ? gbPr1 : gbPr0;
#pragma unroll
            for (int ko = 0; ko < 4; ++ko) bq2[4 + ko] = *(const bf16x8*)&gp[(ko * 64 + l) * 8];
        }

        float vals[8][4];
        float lmax = -INFINITY;
#pragma unroll
        for (int i = 0; i < 8; ++i) {
            const int mt = 8 * w + i;
            const bf16x8* ap = (const bf16x8*)wsO + (size_t)mt * (NKT_O * 64) + l;
            f32x4 a = {0.0f, 0.0f, 0.0f, 0.0f};
#pragma unroll
            for (int kt = 0; kt < NKT_O; ++kt)
                a = __builtin_amdgcn_mfma_f32_16x16x32_bf16(ap[kt * 64], bq2[kt], a, 0, 0, 0);
#pragma unroll
            for (int r = 0; r < 4; ++r) {
                int cls = mt * 16 + 4 * lq + r;
                float v = (cls < LL) ? (a[r] + bout[cls]) : -INFINITY;
                vals[i][r] = v;
                lmax = fmaxf(lmax, v);
                if (cls == labv[ls]) labLogit[ls] = v;
            }
        }
        lmax = fmaxf(lmax, __shfl_xor(lmax, 16, 64));
        lmax = fmaxf(lmax, __shfl_xor(lmax, 32, 64));
        if (l < 16) redm[w][l] = lmax;
        __syncthreads();

        float bm = redm[0][ls];
#pragma unroll
        for (int w2 = 1; w2 < 8; ++w2) bm = fmaxf(bm, redm[w2][ls]);

        float s = 0.0f;
#pragma unroll
        for (int i = 0; i < 8; ++i)
#pragma unroll
            for (int r = 0; r < 4; ++r) s += __expf(vals[i][r] - bm);
        s += __shfl_xor(s, 16, 64);
        s += __shfl_xor(s, 32, 64);
        if (l < 16) reds[w][l] = s;
        __syncthreads();

        if (tid < 16) {
            float bm2 = redm[0][tid], tot = 0.0f;
#pragma unroll
            for (int w2 = 1; w2 < 8; ++w2) bm2 = fmaxf(bm2, redm[w2][tid]);
#pragma unroll
            for (int w2 = 0; w2 < 8; ++w2) tot += reds[w2][tid];
            float lp = labLogit[tid] - bm2 - __logf(tot);
            atomicAdd(&out[HH], -lp * (1.0f / NSEQ));
        }
    }
}

extern "C" void kernel_launch(void* const* d_in, const int* in_sizes, int n_in,
                              void* d_out, int out_size, void* d_ws, size_t ws_size,
                              hipStream_t stream)
{
    const int*   tokens  = (const int*)d_in[0];
    const int*   lengths = (const int*)d_in[1];
    const int*   labels  = (const int*)d_in[2];
    const float* emb     = (const float*)d_in[3];
    const float* Wih     = (const float*)d_in[4];
    const float* Whh     = (const float*)d_in[5];
    const float* bih     = (const float*)d_in[6];
    const float* bhh     = (const float*)d_in[7];
    const float* Wout    = (const float*)d_in[8];
    const float* bout    = (const float*)d_in[9];
    float* out = (float*)d_out;

    unsigned short* wsA  = (unsigned short*)d_ws;
    unsigned short* wsO  = wsA + WSA_ELEMS;
    unsigned short* hbuf = wsO + WSO_ELEMS;
    int*            flg  = (int*)(hbuf + HBUF_ELEMS);   // total ws ~3.3 MB

    hipLaunchKernelGGL(init_out_kernel, dim3(1), dim3(512), 0, stream, out, flg);
    {
        int nthr = NMT * NKT * 64 + NMT * NKT_O * 64;
        hipLaunchKernelGGL(convert_weights, dim3((nthr + 255) / 256), dim3(256), 0, stream,
                           Wih, Whh, Wout, wsA, wsO);
    }
    hipLaunchKernelGGL(lstm_pair_kernel, dim3(NBLK), dim3(NT), 0, stream,
                       tokens, lengths, labels, emb, bih, bhh, bout, wsA, wsO, hbuf, flg, out);
}

// Round 6
// 2826.712 us; speedup vs baseline: 1.3509x; 1.2918x over previous
//
#include <hip/hip_runtime.h>
#include <hip/hip_bf16.h>
#include <math.h>

// Problem constants
#define NSEQ 2048
#define TT   128
#define EE   128
#define HH   256
#define GG   1024
#define LL   1000
#define NT   512        // 8 waves
#define NGRP 32         // groups of 64 seqs
#define NMEM 8          // members (blocks) per group; member owns 32 h-units
#define SEQG 64
#define NKT  12         // K-tiles of 32: 4 x + 8 h
#define NMT  64
#define NKT_O 8
#define WSA_ELEMS (NMT * NKT * 64 * 8)      // 768 KB bf16
#define WSO_ELEMS (NMT * NKT_O * 64 * 8)    // 512 KB bf16
// ghf: [grp][member][parity][cg][64 lanes][8 shorts] = 2 MB
#define GHF_SHORTS ((size_t)NGRP * NMEM * 2 * 4 * 64 * 8)

typedef __attribute__((ext_vector_type(8))) short bf16x8;
typedef __attribute__((ext_vector_type(4))) float f32x4;

__device__ __forceinline__ unsigned short f2bf(float f) {
    union { float f; unsigned u; } v; v.f = f;
    unsigned r = v.u + 0x7FFF + ((v.u >> 16) & 1);   // RNE
    return (unsigned short)(r >> 16);
}
__device__ __forceinline__ float sigf(float x) { return 1.0f / (1.0f + __expf(-x)); }
__device__ __forceinline__ float tanh_fast(float x) { return 1.0f - 2.0f / (1.0f + __expf(2.0f * x)); }

__global__ void init_out_kernel(float* out, int* flags) {
    int i = blockIdx.x * blockDim.x + threadIdx.x;
    if (i < HH + 1) out[i] = 0.0f;
    if (i < NGRP * NMEM) flags[i] = 0;
}

// Pre-shuffle weights into MFMA A-fragment order, bf16 (layout verified R2-R5).
__global__ void convert_weights(const float* __restrict__ Wih, const float* __restrict__ Whh,
                                const float* __restrict__ Wout,
                                unsigned short* __restrict__ wsA, unsigned short* __restrict__ wsO) {
    int gid = blockIdx.x * blockDim.x + threadIdx.x;
    if (gid < NMT * NKT * 64) {
        int lane = gid & 63, tile = gid >> 6;
        int kt = tile % NKT, mt = tile / NKT;
        int row = mt * 16 + (lane & 15);
        int kb  = kt * 32 + (lane >> 4) * 8;
        unsigned short o[8];
#pragma unroll
        for (int j = 0; j < 8; ++j) {
            int k = kb + j;
            float v = (k < EE) ? Wih[row * EE + k] : Whh[row * HH + (k - EE)];
            o[j] = f2bf(v);
        }
        uint4 pk;
        pk.x = o[0] | ((unsigned)o[1] << 16); pk.y = o[2] | ((unsigned)o[3] << 16);
        pk.z = o[4] | ((unsigned)o[5] << 16); pk.w = o[6] | ((unsigned)o[7] << 16);
        *(uint4*)(wsA + (size_t)gid * 8) = pk;
    } else {
        int g2 = gid - NMT * NKT * 64;
        if (g2 < NMT * NKT_O * 64) {
            int lane = g2 & 63, tile = g2 >> 6;
            int kt = tile % NKT_O, mt = tile / NKT_O;
            int row = mt * 16 + (lane & 15);
            int ub  = kt * 32 + (lane >> 4) * 8;
            unsigned short o[8];
#pragma unroll
            for (int j = 0; j < 8; ++j)
                o[j] = (row < LL) ? f2bf(Wout[row * HH + ub + j]) : (unsigned short)0;
            uint4 pk;
            pk.x = o[0] | ((unsigned)o[1] << 16); pk.y = o[2] | ((unsigned)o[3] << 16);
            pk.z = o[4] | ((unsigned)o[5] << 16); pk.w = o[6] | ((unsigned)o[7] << 16);
            *(uint4*)(wsO + (size_t)g2 * 8) = pk;
        }
    }
}

// wait until all 8 member flags >= need (lane-parallel poll, wave-uniform result)
__device__ __forceinline__ void wait_flags(int* base, int lane, int need) {
    while (true) {
        int f = 0x7fffffff;
        if (lane < NMEM)
            f = __hip_atomic_load(&base[lane], __ATOMIC_RELAXED, __HIP_MEMORY_SCOPE_AGENT);
        f = min(f, __shfl_xor(f, 1, 64));
        f = min(f, __shfl_xor(f, 2, 64));
        f = min(f, __shfl_xor(f, 4, 64));
        f = __shfl(f, 0, 64);
        if (f >= need) break;
        __builtin_amdgcn_s_sleep(4);
    }
    (void)__hip_atomic_load(&base[0], __ATOMIC_ACQUIRE, __HIP_MEMORY_SCOPE_AGENT);
}

// 8-way split LSTM: group of 8 blocks handles 64 seqs; member m owns 32 h-units.
// A-frags (96 KB) LDS-resident; h exchanged as ready-made B-frag tiles via L2.
__launch_bounds__(NT, 2)
__global__ void lstm_group_kernel(
    const int* __restrict__ tokens, const int* __restrict__ lengths,
    const int* __restrict__ labels, const float* __restrict__ emb,
    const float* __restrict__ bih,  const float* __restrict__ bhh,
    const float* __restrict__ bout,
    const unsigned short* __restrict__ wsA, const unsigned short* __restrict__ wsO,
    unsigned short* __restrict__ ghf, int* __restrict__ flags,
    float* __restrict__ out)
{
    __shared__ __align__(16) unsigned short wlds[8 * 12 * 64 * 8];   // 96 KB A-frags
    __shared__ __align__(16) unsigned short xf[2 * 4 * 4 * 64 * 8];  // 32 KB x B-frags (dbuf)
    __shared__ __align__(16) unsigned short hf[2 * 4 * 64 * 8];      // 8 KB own-h B-frags (dbuf)
    __shared__ float bias_s[128];
    __shared__ int   labv[SEQG];

    const int tid = threadIdx.x;
    const int w   = tid >> 6;
    const int l   = tid & 63;
    const int lq  = l >> 4;
    const int ls  = l & 15;
    const int jj  = w >> 2;        // row half (0/1) of each gate's 32-row tile-pair
    const int cg  = w & 3;         // col group (16 seqs)
    const int grp = blockIdx.x & (NGRP - 1);
    const int m   = blockIdx.x >> 5;     // member: blocks {grp + 32*m} share XCD under %8
    const int n0  = grp * SEQG;

    int* const flagBase = flags + grp * NMEM;

    // maxlen over the group's 64 seqs (uniform across all 8 members!)
    int maxlen = lengths[n0 + l];
#pragma unroll
    for (int s = 1; s < 64; s <<= 1) maxlen = max(maxlen, __shfl_xor(maxlen, s, 64));
    const int len_s = lengths[n0 + cg * 16 + ls];

    if (tid < SEQG) labv[tid] = labels[n0 + tid];
    if (tid < 128) {
        int g = tid >> 5, u = tid & 31;
        int row = 256 * g + 32 * m + u;
        bias_s[tid] = bih[row] + bhh[row];
    }

    // ---- one-time: this member's A-frags (8 mt x 12 kt) -> LDS ----
    for (int idx = tid; idx < 8 * 12 * 64; idx += NT) {
        int mtl = idx / 768;
        int rem = idx - mtl * 768;
        int kt = rem >> 6, l2 = rem & 63;
        int g = mtl >> 1, j2 = mtl & 1;
        int gmt = 16 * g + 2 * m + j2;         // global M-tile in wsA
        *(uint4*)&wlds[(size_t)idx * 8] =
            *(const uint4*)(wsA + ((size_t)(gmt * NKT + kt) * 64 + l2) * 8);
    }

    // zero hf buf0 + ghf parity0 slice (h(0) = 0)
    if (tid < 256) {
        uint4 z = {0, 0, 0, 0};
        *(uint4*)&hf[(size_t)tid * 8] = z;
        size_t base = ((size_t)((grp * NMEM + m) * 2 + 0) * 4) * 512;
        *(uint4*)&ghf[base + (size_t)tid * 8] = z;
    }

    // x staging map: thread -> (seq, 16-dim octet)
    const int xs_s   = tid & 63;
    const int xs_oct = tid >> 6;

    // stage x(0) into xf buf0
    {
        int tok = tokens[(n0 + xs_s) * TT + 0];
        const float* er = emb + (size_t)tok * EE + 16 * xs_oct;
#pragma unroll
        for (int dc = 0; dc < 4; ++dc) {
            f32x4 xv = *(const f32x4*)(er + 4 * dc);
            int d0 = 16 * xs_oct + 4 * dc;
            int kt = d0 >> 5, cgs = xs_s >> 4;
            int lanep = (xs_s & 15) + 16 * ((d0 >> 3) & 3);
            uint2 pk;
            pk.x = f2bf(xv[0]) | ((unsigned)f2bf(xv[1]) << 16);
            pk.y = f2bf(xv[2]) | ((unsigned)f2bf(xv[3]) << 16);
            *(uint2*)&xf[(size_t)(((0 * 4 + kt) * 4 + cgs) * 64 + lanep) * 8 + (d0 & 4)] = pk;
        }
    }
    __syncthreads();
    if (tid == 0)
        __hip_atomic_fetch_add(&flagBase[m], 1, __ATOMIC_RELEASE, __HIP_MEMORY_SCOPE_AGENT);

    float c_reg[4], h_reg[4];
#pragma unroll
    for (int r = 0; r < 4; ++r) { c_reg[r] = 0.0f; h_reg[r] = 0.0f; }

    // h publish mapping: unit u = 16*jj + 4*lq + r in member's 32-k tile (kt = 4+m)
    const int u8      = 2 * jj + (lq >> 1);          // u>>3
    const int lanep_h = 16 * u8 + ls;
    const int joff_h  = 4 * (lq & 1);
    const size_t gb0  = ((size_t)((grp * NMEM + m) * 2 + 0) * 4 + cg) * 512 + (size_t)lanep_h * 8 + joff_h;
    const size_t gb1  = gb0 + 4 * 512;               // parity stride

    // ---- recurrence: ONE barrier + one flag add per step ----
    for (int t = 0; t < maxlen; ++t) {
        const int cur = t & 1, nxt = cur ^ 1;

        // own B-frags from LDS (cur buffers)
        bf16x8 bx[4];
#pragma unroll
        for (int kt = 0; kt < 4; ++kt)
            bx[kt] = *(const bf16x8*)&xf[(size_t)(((cur * 4 + kt) * 4 + cg) * 64 + l) * 8];
        const bf16x8 bo = *(const bf16x8*)&hf[(size_t)((cur * 4 + cg) * 64 + l) * 8];

        // prefetch x(t+1) (plain loads: members share rows via XCD L2)
        const bool doX = (t + 1 < maxlen);
        f32x4 xv[4];
        if (doX) {
            int tok = tokens[(n0 + xs_s) * TT + t + 1];
            const float* er = emb + (size_t)tok * EE + 16 * xs_oct;
#pragma unroll
            for (int dc = 0; dc < 4; ++dc) xv[dc] = *(const f32x4*)(er + 4 * dc);
        }

        // wait for all members' h(t), then issue the 7 partner B-frag loads
        wait_flags(flagBase, l, t + 1);
        bf16x8 bp[7];
#pragma unroll
        for (int i = 0; i < 7; ++i) {
            int p = i + (i >= m ? 1 : 0);
            size_t b = ((size_t)((grp * NMEM + p) * 2 + cur) * 4 + cg) * 512;
            bp[i] = *(const bf16x8*)&ghf[b + (size_t)l * 8];
        }

        f32x4 acc[4];
#pragma unroll
        for (int g = 0; g < 4; ++g)
            acc[g] = *(const f32x4*)&bias_s[g * 32 + 16 * jj + 4 * lq];

        // x part (overlaps partner-load latency)
#pragma unroll
        for (int kt = 0; kt < 4; ++kt)
#pragma unroll
            for (int g = 0; g < 4; ++g)
                acc[g] = __builtin_amdgcn_mfma_f32_16x16x32_bf16(
                    *(const bf16x8*)&wlds[(size_t)(((2 * g + jj) * 12 + kt) * 64 + l) * 8],
                    bx[kt], acc[g], 0, 0, 0);
        // own-h part (kt = 4+m)
#pragma unroll
        for (int g = 0; g < 4; ++g)
            acc[g] = __builtin_amdgcn_mfma_f32_16x16x32_bf16(
                *(const bf16x8*)&wlds[(size_t)(((2 * g + jj) * 12 + 4 + m) * 64 + l) * 8],
                bo, acc[g], 0, 0, 0);
        // partner-h parts
#pragma unroll
        for (int i = 0; i < 7; ++i) {
            int p = i + (i >= m ? 1 : 0);
            int kt = 4 + p;
#pragma unroll
            for (int g = 0; g < 4; ++g)
                acc[g] = __builtin_amdgcn_mfma_f32_16x16x32_bf16(
                    *(const bf16x8*)&wlds[(size_t)(((2 * g + jj) * 12 + kt) * 64 + l) * 8],
                    bp[i], acc[g], 0, 0, 0);
        }

        // in-register cell update (i,f,g,o aligned per thread)
        const bool live = (t < len_s);
#pragma unroll
        for (int r = 0; r < 4; ++r) {
            if (live) {
                float ig = sigf(acc[0][r]);
                float fg = sigf(acc[1][r]);
                float gg = tanh_fast(acc[2][r]);
                float og = sigf(acc[3][r]);
                float cc = fg * c_reg[r] + ig * gg;
                c_reg[r] = cc;
                h_reg[r] = og * tanh_fast(cc);
            }
        }

        // publish h(t+1): LDS nxt buffer + global frag (parity (t+1)&1)
        {
            uint2 hp;
            hp.x = f2bf(h_reg[0]) | ((unsigned)f2bf(h_reg[1]) << 16);
            hp.y = f2bf(h_reg[2]) | ((unsigned)f2bf(h_reg[3]) << 16);
            *(uint2*)&hf[(size_t)((nxt * 4 + cg) * 64 + lanep_h) * 8 + joff_h] = hp;
            *(uint2*)&ghf[((t + 1) & 1) ? gb1 : gb0] = hp;
        }
        // stage x(t+1) into xf[nxt]
        if (doX) {
#pragma unroll
            for (int dc = 0; dc < 4; ++dc) {
                int d0 = 16 * xs_oct + 4 * dc;
                int kt = d0 >> 5, cgs = xs_s >> 4;
                int lanep = (xs_s & 15) + 16 * ((d0 >> 3) & 3);
                uint2 pk;
                pk.x = f2bf(xv[dc][0]) | ((unsigned)f2bf(xv[dc][1]) << 16);
                pk.y = f2bf(xv[dc][2]) | ((unsigned)f2bf(xv[dc][3]) << 16);
                *(uint2*)&xf[(size_t)(((nxt * 4 + kt) * 4 + cgs) * 64 + lanep) * 8 + (d0 & 4)] = pk;
            }
        }

        __syncthreads();   // drains LDS + vmem (ghf stores) before flag release
        if (tid == 0)
            __hip_atomic_fetch_add(&flagBase[m], 1, __ATOMIC_RELEASE, __HIP_MEMORY_SCOPE_AGENT);
    }

    // ---- epilogue 1: embeds = mean(c_f) for own 32 units ----
#pragma unroll
    for (int r = 0; r < 4; ++r) {
        float v = c_reg[r];
        v += __shfl_xor(v, 1, 64);
        v += __shfl_xor(v, 2, 64);
        v += __shfl_xor(v, 4, 64);
        v += __shfl_xor(v, 8, 64);
        if (ls == 0)
            atomicAdd(&out[32 * m + 16 * jj + 4 * lq + r], v * (1.0f / NSEQ));
    }

    // ---- epilogue 2 (member 0): logits GEMM + log-softmax for the 64 seqs ----
    if (m == 0) {
        wait_flags(flagBase, l, maxlen + 1);
        const int fin = maxlen & 1;
        float* lg = (float*)wlds;            // reuse: 16 seqs x 1024 logits (64 KB)
        float lossAcc = 0.0f;

        for (int cgo = 0; cgo < 4; ++cgo) {
            // B-frags: member p's final-h tile IS k-tile p of the 256-k GEMM
            bf16x8 bq[8];
#pragma unroll
            for (int p = 0; p < 8; ++p) {
                size_t b = ((size_t)((grp * NMEM + p) * 2 + fin) * 4 + cgo) * 512;
                bq[p] = *(const bf16x8*)&ghf[b + (size_t)l * 8];
            }
            __syncthreads();   // previous cgo's softmax reads of lg are done
#pragma unroll
            for (int i = 0; i < 8; ++i) {
                int mt = 8 * w + i;
                f32x4 a = {0.0f, 0.0f, 0.0f, 0.0f};
#pragma unroll
                for (int p = 0; p < 8; ++p)
                    a = __builtin_amdgcn_mfma_f32_16x16x32_bf16(
                        *(const bf16x8*)(wsO + ((size_t)(mt * NKT_O + p) * 64 + l) * 8),
                        bq[p], a, 0, 0, 0);
#pragma unroll
                for (int r = 0; r < 4; ++r) {
                    int cls = 16 * mt + 4 * lq + r;
                    lg[(size_t)ls * 1024 + cls] = (cls < LL) ? (a[r] + bout[cls]) : -INFINITY;
                }
            }
            __syncthreads();
            // per-seq log-softmax: 32 threads per seq over 1024 slots
            const int s2 = tid >> 5;     // 0..15
            const int i2 = tid & 31;
            const float* row = &lg[(size_t)s2 * 1024];
            float mx = -INFINITY;
#pragma unroll
            for (int k = 0; k < 32; ++k) mx = fmaxf(mx, row[i2 + 32 * k]);
            mx = fmaxf(mx, __shfl_xor(mx, 1, 64));
            mx = fmaxf(mx, __shfl_xor(mx, 2, 64));
            mx = fmaxf(mx, __shfl_xor(mx, 4, 64));
            mx = fmaxf(mx, __shfl_xor(mx, 8, 64));
            mx = fmaxf(mx, __shfl_xor(mx, 16, 64));
            float sm = 0.0f;
#pragma unroll
            for (int k = 0; k < 32; ++k) sm += __expf(row[i2 + 32 * k] - mx);
            sm += __shfl_xor(sm, 1, 64);
            sm += __shfl_xor(sm, 2, 64);
            sm += __shfl_xor(sm, 4, 64);
            sm += __shfl_xor(sm, 8, 64);
            sm += __shfl_xor(sm, 16, 64);
            if (i2 == 0) {
                int lab = labv[cgo * 16 + s2];
                float lp = row[lab] - mx - __logf(sm);
                lossAcc += -lp;
            }
        }
        if ((tid & 31) == 0)
            atomicAdd(&out[HH], lossAcc * (1.0f / NSEQ));
    }
}

extern "C" void kernel_launch(void* const* d_in, const int* in_sizes, int n_in,
                              void* d_out, int out_size, void* d_ws, size_t ws_size,
                              hipStream_t stream)
{
    const int*   tokens  = (const int*)d_in[0];
    const int*   lengths = (const int*)d_in[1];
    const int*   labels  = (const int*)d_in[2];
    const float* emb     = (const float*)d_in[3];
    const float* Wih     = (const float*)d_in[4];
    const float* Whh     = (const float*)d_in[5];
    const float* bih     = (const float*)d_in[6];
    const float* bhh     = (const float*)d_in[7];
    const float* Wout    = (const float*)d_in[8];
    const float* bout    = (const float*)d_in[9];
    float* out = (float*)d_out;

    unsigned short* wsA  = (unsigned short*)d_ws;
    unsigned short* wsO  = wsA + WSA_ELEMS;
    unsigned short* ghf  = wsO + WSO_ELEMS;
    int*            flg  = (int*)(ghf + GHF_SHORTS);   // total ws ~3.3 MB

    hipLaunchKernelGGL(init_out_kernel, dim3(1), dim3(512), 0, stream, out, flg);
    {
        int nthr = NMT * NKT * 64 + NMT * NKT_O * 64;
        hipLaunchKernelGGL(convert_weights, dim3((nthr + 255) / 256), dim3(256), 0, stream,
                           Wih, Whh, Wout, wsA, wsO);
    }
    hipLaunchKernelGGL(lstm_group_kernel, dim3(NGRP * NMEM), dim3(NT), 0, stream,
                       tokens, lengths, labels, emb, bih, bhh, bout, wsA, wsO, ghf, flg, out);
}

// Round 7
// 708.832 us; speedup vs baseline: 5.3872x; 3.9878x over previous
//
#include <hip/hip_runtime.h>
#include <hip/hip_bf16.h>
#include <math.h>

// Problem constants
#define NSEQ 2048
#define TT   128
#define EE   128
#define HH   256
#define GG   1024
#define LL   1000
#define NT   512        // 8 waves
#define NGRP 32         // groups of 64 seqs
#define NMEM 8          // members (blocks) per group; member owns 32 h-units
#define SEQG 64
#define NKT  12         // K-tiles of 32: 4 x + 8 h
#define NMT  64
#define NKT_O 8
#define WSA_ELEMS (NMT * NKT * 64 * 8)      // 768 KB bf16
#define WSO_ELEMS (NMT * NKT_O * 64 * 8)    // 512 KB bf16
// ghf: [grp][member][parity][cg][64 lanes][8 shorts] = 2 MB
#define GHF_SHORTS ((size_t)NGRP * NMEM * 2 * 4 * 64 * 8)

typedef __attribute__((ext_vector_type(8))) short bf16x8;
typedef __attribute__((ext_vector_type(4))) float f32x4;
typedef unsigned long long u64;

__device__ __forceinline__ unsigned short f2bf(float f) {
    union { float f; unsigned u; } v; v.f = f;
    unsigned r = v.u + 0x7FFF + ((v.u >> 16) & 1);   // RNE
    return (unsigned short)(r >> 16);
}
__device__ __forceinline__ float sigf(float x) { return 1.0f / (1.0f + __expf(-x)); }
__device__ __forceinline__ float tanh_fast(float x) { return 1.0f - 2.0f / (1.0f + __expf(2.0f * x)); }

// system-scope relaxed 8B ops: sc0+sc1 (bypass L1/L2, served at L3) — NO wbl2/inv
__device__ __forceinline__ void st8_sys(unsigned short* p, unsigned lo, unsigned hi) {
    u64 v = (u64)lo | ((u64)hi << 32);
    __hip_atomic_store((u64*)p, v, __ATOMIC_RELAXED, __HIP_MEMORY_SCOPE_SYSTEM);
}
__device__ __forceinline__ bf16x8 ld16_sys(const unsigned short* p) {
    u64 lo = __hip_atomic_load((const u64*)p,       __ATOMIC_RELAXED, __HIP_MEMORY_SCOPE_SYSTEM);
    u64 hi = __hip_atomic_load((const u64*)(p + 4), __ATOMIC_RELAXED, __HIP_MEMORY_SCOPE_SYSTEM);
    union { u64 q[2]; bf16x8 v; } u; u.q[0] = lo; u.q[1] = hi;
    return u.v;
}

__global__ void init_out_kernel(float* out, int* flags) {
    int i = blockIdx.x * blockDim.x + threadIdx.x;
    if (i < HH + 1) out[i] = 0.0f;
    if (i < NGRP * NMEM) flags[i] = 0;
}

// Pre-shuffle weights into MFMA A-fragment order, bf16 (layout verified R2-R6).
__global__ void convert_weights(const float* __restrict__ Wih, const float* __restrict__ Whh,
                                const float* __restrict__ Wout,
                                unsigned short* __restrict__ wsA, unsigned short* __restrict__ wsO) {
    int gid = blockIdx.x * blockDim.x + threadIdx.x;
    if (gid < NMT * NKT * 64) {
        int lane = gid & 63, tile = gid >> 6;
        int kt = tile % NKT, mt = tile / NKT;
        int row = mt * 16 + (lane & 15);
        int kb  = kt * 32 + (lane >> 4) * 8;
        unsigned short o[8];
#pragma unroll
        for (int j = 0; j < 8; ++j) {
            int k = kb + j;
            float v = (k < EE) ? Wih[row * EE + k] : Whh[row * HH + (k - EE)];
            o[j] = f2bf(v);
        }
        uint4 pk;
        pk.x = o[0] | ((unsigned)o[1] << 16); pk.y = o[2] | ((unsigned)o[3] << 16);
        pk.z = o[4] | ((unsigned)o[5] << 16); pk.w = o[6] | ((unsigned)o[7] << 16);
        *(uint4*)(wsA + (size_t)gid * 8) = pk;
    } else {
        int g2 = gid - NMT * NKT * 64;
        if (g2 < NMT * NKT_O * 64) {
            int lane = g2 & 63, tile = g2 >> 6;
            int kt = tile % NKT_O, mt = tile / NKT_O;
            int row = mt * 16 + (lane & 15);
            int ub  = kt * 32 + (lane >> 4) * 8;
            unsigned short o[8];
#pragma unroll
            for (int j = 0; j < 8; ++j)
                o[j] = (row < LL) ? f2bf(Wout[row * HH + ub + j]) : (unsigned short)0;
            uint4 pk;
            pk.x = o[0] | ((unsigned)o[1] << 16); pk.y = o[2] | ((unsigned)o[3] << 16);
            pk.z = o[4] | ((unsigned)o[5] << 16); pk.w = o[6] | ((unsigned)o[7] << 16);
            *(uint4*)(wsO + (size_t)g2 * 8) = pk;
        }
    }
}

// 8-way split LSTM. Sync fabric: relaxed system-scope atomics (L3) + LDS relay.
__launch_bounds__(NT, 2)
__global__ void lstm_group_kernel(
    const int* __restrict__ tokens, const int* __restrict__ lengths,
    const int* __restrict__ labels, const float* __restrict__ emb,
    const float* __restrict__ bih,  const float* __restrict__ bhh,
    const float* __restrict__ bout,
    const unsigned short* __restrict__ wsA, const unsigned short* __restrict__ wsO,
    unsigned short* __restrict__ ghf, int* __restrict__ flags,
    float* __restrict__ out)
{
    __shared__ __align__(16) unsigned short wlds[8 * 12 * 64 * 8];   // 96 KB A-frags
    __shared__ __align__(16) unsigned short xf[2 * 4 * 4 * 64 * 8];  // 32 KB x B-frags (dbuf)
    __shared__ __align__(16) unsigned short hf[2 * 4 * 64 * 8];      // 8 KB own-h B-frags (dbuf)
    __shared__ float bias_s[128];
    __shared__ int   labv[SEQG];
    __shared__ int   ready_s;

    const int tid = threadIdx.x;
    const int w   = tid >> 6;
    const int l   = tid & 63;
    const int lq  = l >> 4;
    const int ls  = l & 15;
    const int jj  = w >> 2;        // row half (0/1) of each gate's 32-row tile-pair
    const int cg  = w & 3;         // col group (16 seqs)
    const int grp = blockIdx.x & (NGRP - 1);
    const int m   = blockIdx.x >> 5;
    const int n0  = grp * SEQG;

    int* const flagBase = flags + grp * NMEM;

    // maxlen over the group's 64 seqs (uniform across all 8 members)
    int maxlen = lengths[n0 + l];
#pragma unroll
    for (int s = 1; s < 64; s <<= 1) maxlen = max(maxlen, __shfl_xor(maxlen, s, 64));
    const int len_s = lengths[n0 + cg * 16 + ls];

    if (tid < SEQG) labv[tid] = labels[n0 + tid];
    if (tid < 128) {
        int g = tid >> 5, u = tid & 31;
        int row = 256 * g + 32 * m + u;
        bias_s[tid] = bih[row] + bhh[row];
    }
    if (tid == 0) ready_s = 0;

    // ---- one-time: this member's A-frags (8 mt x 12 kt) -> LDS ----
    for (int idx = tid; idx < 8 * 12 * 64; idx += NT) {
        int mtl = idx / 768;
        int rem = idx - mtl * 768;
        int kt = rem >> 6, l2 = rem & 63;
        int g = mtl >> 1, j2 = mtl & 1;
        int gmt = 16 * g + 2 * m + j2;
        *(uint4*)&wlds[(size_t)idx * 8] =
            *(const uint4*)(wsA + ((size_t)(gmt * NKT + kt) * 64 + l2) * 8);
    }

    // zero hf buf0 + ghf parity0 slice (h(0) = 0), ghf via system stores
    if (tid < 256) {
        uint4 z = {0, 0, 0, 0};
        *(uint4*)&hf[(size_t)tid * 8] = z;
        size_t base = ((size_t)((grp * NMEM + m) * 2 + 0) * 4) * 512 + (size_t)tid * 8;
        st8_sys(&ghf[base], 0, 0);
        st8_sys(&ghf[base + 4], 0, 0);
    }

    // x staging map: thread -> (seq, 16-dim octet)
    const int xs_s   = tid & 63;
    const int xs_oct = tid >> 6;

    // stage x(0) into xf buf0
    {
        int tok = tokens[(n0 + xs_s) * TT + 0];
        const float* er = emb + (size_t)tok * EE + 16 * xs_oct;
#pragma unroll
        for (int dc = 0; dc < 4; ++dc) {
            f32x4 xv = *(const f32x4*)(er + 4 * dc);
            int d0 = 16 * xs_oct + 4 * dc;
            int kt = d0 >> 5, cgs = xs_s >> 4;
            int lanep = (xs_s & 15) + 16 * ((d0 >> 3) & 3);
            uint2 pk;
            pk.x = f2bf(xv[0]) | ((unsigned)f2bf(xv[1]) << 16);
            pk.y = f2bf(xv[2]) | ((unsigned)f2bf(xv[3]) << 16);
            *(uint2*)&xf[(size_t)(((0 * 4 + kt) * 4 + cgs) * 64 + lanep) * 8 + (d0 & 4)] = pk;
        }
    }
    __syncthreads();   // drains vmcnt (system stores at L3) + LDS
    if (tid == 0)
        __hip_atomic_store(&flagBase[m], 1, __ATOMIC_RELAXED, __HIP_MEMORY_SCOPE_SYSTEM);

    // relay wait: wave0 polls flags at L3; other waves spin on LDS (no fabric traffic)
    auto relay_wait = [&](int need) {
        if (w == 0) {
            int f;
            do {
                f = 0x7fffffff;
                if (l < NMEM)
                    f = __hip_atomic_load(&flagBase[l], __ATOMIC_RELAXED, __HIP_MEMORY_SCOPE_SYSTEM);
                f = min(f, __shfl_xor(f, 1, 64));
                f = min(f, __shfl_xor(f, 2, 64));
                f = min(f, __shfl_xor(f, 4, 64));
                f = __shfl(f, 0, 64);
                if (f < need) __builtin_amdgcn_s_sleep(2);
            } while (f < need);
            __hip_atomic_store(&ready_s, need, __ATOMIC_RELEASE, __HIP_MEMORY_SCOPE_WORKGROUP);
        } else {
            while (__hip_atomic_load(&ready_s, __ATOMIC_ACQUIRE, __HIP_MEMORY_SCOPE_WORKGROUP) < need)
                __builtin_amdgcn_s_sleep(1);
        }
    };

    float c_reg[4], h_reg[4];
#pragma unroll
    for (int r = 0; r < 4; ++r) { c_reg[r] = 0.0f; h_reg[r] = 0.0f; }

    // h publish mapping: unit u = 16*jj + 4*lq + r in member's 32-k tile
    const int u8      = 2 * jj + (lq >> 1);
    const int lanep_h = 16 * u8 + ls;
    const int joff_h  = 4 * (lq & 1);
    const size_t gb0  = ((size_t)((grp * NMEM + m) * 2 + 0) * 4 + cg) * 512 + (size_t)lanep_h * 8 + joff_h;
    const size_t gb1  = gb0 + 4 * 512;

    // ---- recurrence ----
    for (int t = 0; t < maxlen; ++t) {
        const int cur = t & 1, nxt = cur ^ 1;

        // own B-frags from LDS (cur buffers)
        bf16x8 bx[4];
#pragma unroll
        for (int kt = 0; kt < 4; ++kt)
            bx[kt] = *(const bf16x8*)&xf[(size_t)(((cur * 4 + kt) * 4 + cg) * 64 + l) * 8];
        const bf16x8 bo = *(const bf16x8*)&hf[(size_t)((cur * 4 + cg) * 64 + l) * 8];

        // prefetch x(t+1)
        const bool doX = (t + 1 < maxlen);
        f32x4 xv[4];
        if (doX) {
            int tok = tokens[(n0 + xs_s) * TT + t + 1];
            const float* er = emb + (size_t)tok * EE + 16 * xs_oct;
#pragma unroll
            for (int dc = 0; dc < 4; ++dc) xv[dc] = *(const f32x4*)(er + 4 * dc);
        }

        f32x4 acc[4];
#pragma unroll
        for (int g = 0; g < 4; ++g)
            acc[g] = *(const f32x4*)&bias_s[g * 32 + 16 * jj + 4 * lq];

        // x part BEFORE the wait (independent of partners)
#pragma unroll
        for (int kt = 0; kt < 4; ++kt)
#pragma unroll
            for (int g = 0; g < 4; ++g)
                acc[g] = __builtin_amdgcn_mfma_f32_16x16x32_bf16(
                    *(const bf16x8*)&wlds[(size_t)(((2 * g + jj) * 12 + kt) * 64 + l) * 8],
                    bx[kt], acc[g], 0, 0, 0);

        // wait for all members' h(t)
        relay_wait(t + 1);

        // issue 7 partner B-frag loads (L3, fresh by construction)
        bf16x8 bp[7];
#pragma unroll
        for (int i = 0; i < 7; ++i) {
            int p = i + (i >= m ? 1 : 0);
            size_t b = ((size_t)((grp * NMEM + p) * 2 + cur) * 4 + cg) * 512;
            bp[i] = ld16_sys(&ghf[b + (size_t)l * 8]);
        }

        // own-h part (hides partner-load latency)
#pragma unroll
        for (int g = 0; g < 4; ++g)
            acc[g] = __builtin_amdgcn_mfma_f32_16x16x32_bf16(
                *(const bf16x8*)&wlds[(size_t)(((2 * g + jj) * 12 + 4 + m) * 64 + l) * 8],
                bo, acc[g], 0, 0, 0);
        // partner-h parts
#pragma unroll
        for (int i = 0; i < 7; ++i) {
            int p = i + (i >= m ? 1 : 0);
            int kt = 4 + p;
#pragma unroll
            for (int g = 0; g < 4; ++g)
                acc[g] = __builtin_amdgcn_mfma_f32_16x16x32_bf16(
                    *(const bf16x8*)&wlds[(size_t)(((2 * g + jj) * 12 + kt) * 64 + l) * 8],
                    bp[i], acc[g], 0, 0, 0);
        }

        // in-register cell update
        const bool live = (t < len_s);
#pragma unroll
        for (int r = 0; r < 4; ++r) {
            if (live) {
                float ig = sigf(acc[0][r]);
                float fg = sigf(acc[1][r]);
                float gg = tanh_fast(acc[2][r]);
                float og = sigf(acc[3][r]);
                float cc = fg * c_reg[r] + ig * gg;
                c_reg[r] = cc;
                h_reg[r] = og * tanh_fast(cc);
            }
        }

        // publish h(t+1): LDS nxt buffer + ghf (system store), parity (t+1)&1
        {
            uint2 hp;
            hp.x = f2bf(h_reg[0]) | ((unsigned)f2bf(h_reg[1]) << 16);
            hp.y = f2bf(h_reg[2]) | ((unsigned)f2bf(h_reg[3]) << 16);
            *(uint2*)&hf[(size_t)((nxt * 4 + cg) * 64 + lanep_h) * 8 + joff_h] = hp;
            st8_sys(&ghf[((t + 1) & 1) ? gb1 : gb0], hp.x, hp.y);
        }
        // stage x(t+1) into xf[nxt]
        if (doX) {
#pragma unroll
            for (int dc = 0; dc < 4; ++dc) {
                int d0 = 16 * xs_oct + 4 * dc;
                int kt = d0 >> 5, cgs = xs_s >> 4;
                int lanep = (xs_s & 15) + 16 * ((d0 >> 3) & 3);
                uint2 pk;
                pk.x = f2bf(xv[dc][0]) | ((unsigned)f2bf(xv[dc][1]) << 16);
                pk.y = f2bf(xv[dc][2]) | ((unsigned)f2bf(xv[dc][3]) << 16);
                *(uint2*)&xf[(size_t)(((nxt * 4 + kt) * 4 + cgs) * 64 + lanep) * 8 + (d0 & 4)] = pk;
            }
        }

        __syncthreads();   // drains LDS + vmcnt (ghf system stores visible at L3)
        if (tid == 0)
            __hip_atomic_store(&flagBase[m], t + 2, __ATOMIC_RELAXED, __HIP_MEMORY_SCOPE_SYSTEM);
    }

    // ---- epilogue 1: embeds = mean(c_f) for own 32 units ----
#pragma unroll
    for (int r = 0; r < 4; ++r) {
        float v = c_reg[r];
        v += __shfl_xor(v, 1, 64);
        v += __shfl_xor(v, 2, 64);
        v += __shfl_xor(v, 4, 64);
        v += __shfl_xor(v, 8, 64);
        if (ls == 0)
            atomicAdd(&out[32 * m + 16 * jj + 4 * lq + r], v * (1.0f / NSEQ));
    }

    // ---- epilogue 2 (member 0): logits GEMM + log-softmax for the 64 seqs ----
    if (m == 0) {
        relay_wait(maxlen + 1);
        const int fin = maxlen & 1;
        float* lg = (float*)wlds;            // reuse: 16 seqs x 1024 logits
        float lossAcc = 0.0f;

        for (int cgo = 0; cgo < 4; ++cgo) {
            bf16x8 bq[8];
#pragma unroll
            for (int p = 0; p < 8; ++p) {
                size_t b = ((size_t)((grp * NMEM + p) * 2 + fin) * 4 + cgo) * 512;
                bq[p] = ld16_sys(&ghf[b + (size_t)l * 8]);
            }
            __syncthreads();
#pragma unroll
            for (int i = 0; i < 8; ++i) {
                int mt = 8 * w + i;
                f32x4 a = {0.0f, 0.0f, 0.0f, 0.0f};
#pragma unroll
                for (int p = 0; p < 8; ++p)
                    a = __builtin_amdgcn_mfma_f32_16x16x32_bf16(
                        *(const bf16x8*)(wsO + ((size_t)(mt * NKT_O + p) * 64 + l) * 8),
                        bq[p], a, 0, 0, 0);
#pragma unroll
                for (int r = 0; r < 4; ++r) {
                    int cls = 16 * mt + 4 * lq + r;
                    lg[(size_t)ls * 1024 + cls] = (cls < LL) ? (a[r] + bout[cls]) : -INFINITY;
                }
            }
            __syncthreads();
            const int s2 = tid >> 5;
            const int i2 = tid & 31;
            const float* row = &lg[(size_t)s2 * 1024];
            float mx = -INFINITY;
#pragma unroll
            for (int k = 0; k < 32; ++k) mx = fmaxf(mx, row[i2 + 32 * k]);
            mx = fmaxf(mx, __shfl_xor(mx, 1, 64));
            mx = fmaxf(mx, __shfl_xor(mx, 2, 64));
            mx = fmaxf(mx, __shfl_xor(mx, 4, 64));
            mx = fmaxf(mx, __shfl_xor(mx, 8, 64));
            mx = fmaxf(mx, __shfl_xor(mx, 16, 64));
            float sm = 0.0f;
#pragma unroll
            for (int k = 0; k < 32; ++k) sm += __expf(row[i2 + 32 * k] - mx);
            sm += __shfl_xor(sm, 1, 64);
            sm += __shfl_xor(sm, 2, 64);
            sm += __shfl_xor(sm, 4, 64);
            sm += __shfl_xor(sm, 8, 64);
            sm += __shfl_xor(sm, 16, 64);
            if (i2 == 0) {
                int lab = labv[cgo * 16 + s2];
                float lp = row[lab] - mx - __logf(sm);
                lossAcc += -lp;
            }
        }
        if ((tid & 31) == 0)
            atomicAdd(&out[HH], lossAcc * (1.0f / NSEQ));
    }
}

extern "C" void kernel_launch(void* const* d_in, const int* in_sizes, int n_in,
                              void* d_out, int out_size, void* d_ws, size_t ws_size,
                              hipStream_t stream)
{
    const int*   tokens  = (const int*)d_in[0];
    const int*   lengths = (const int*)d_in[1];
    const int*   labels  = (const int*)d_in[2];
    const float* emb     = (const float*)d_in[3];
    const float* Wih     = (const float*)d_in[4];
    const float* Whh     = (const float*)d_in[5];
    const float* bih     = (const float*)d_in[6];
    const float* bhh     = (const float*)d_in[7];
    const float* Wout    = (const float*)d_in[8];
    const float* bout    = (const float*)d_in[9];
    float* out = (float*)d_out;

    unsigned short* wsA  = (unsigned short*)d_ws;
    unsigned short* wsO  = wsA + WSA_ELEMS;
    unsigned short* ghf  = wsO + WSO_ELEMS;
    int*            flg  = (int*)(ghf + GHF_SHORTS);

    hipLaunchKernelGGL(init_out_kernel, dim3(1), dim3(512), 0, stream, out, flg);
    {
        int nthr = NMT * NKT * 64 + NMT * NKT_O * 64;
        hipLaunchKernelGGL(convert_weights, dim3((nthr + 255) / 256), dim3(256), 0, stream,
                           Wih, Whh, Wout, wsA, wsO);
    }
    hipLaunchKernelGGL(lstm_group_kernel, dim3(NGRP * NMEM), dim3(NT), 0, stream,
                       tokens, lengths, labels, emb, bih, bhh, bout, wsA, wsO, ghf, flg, out);
}

// Round 8
// 700.748 us; speedup vs baseline: 5.4494x; 1.0115x over previous
//
#include <hip/hip_runtime.h>
#include <hip/hip_bf16.h>
#include <math.h>

// Problem constants
#define NSEQ 2048
#define TT   128
#define EE   128
#define HH   256
#define GG   1024
#define LL   1000
#define NT   512        // 8 waves
#define NGRP 32         // groups of 64 seqs
#define NMEM 8          // members (blocks) per group; member owns 32 h-units
#define SEQG 64
#define NKT  12         // K-tiles of 32: 4 x + 8 h
#define NMT  64
#define NKT_O 8
#define WSA_ELEMS (NMT * NKT * 64 * 8)      // 768 KB bf16
#define WSO_ELEMS (NMT * NKT_O * 64 * 8)    // 512 KB bf16
// ghf: [grp][member][parity][cg][64 lanes][8 shorts] = 2 MB
#define GHF_SHORTS ((size_t)NGRP * NMEM * 2 * 4 * 64 * 8)

typedef __attribute__((ext_vector_type(8))) short bf16x8;
typedef __attribute__((ext_vector_type(4))) float f32x4;
typedef unsigned long long u64;

__device__ __forceinline__ unsigned short f2bf(float f) {
    union { float f; unsigned u; } v; v.f = f;
    unsigned r = v.u + 0x7FFF + ((v.u >> 16) & 1);   // RNE
    return (unsigned short)(r >> 16);
}
__device__ __forceinline__ float sigf(float x) { return 1.0f / (1.0f + __expf(-x)); }
__device__ __forceinline__ float tanh_fast(float x) { return 1.0f - 2.0f / (1.0f + __expf(2.0f * x)); }

// system-scope relaxed 8B ops: sc0+sc1 (served at L3) — NO wbl2/buffer_inv
__device__ __forceinline__ void st8_sys(unsigned short* p, unsigned lo, unsigned hi) {
    u64 v = (u64)lo | ((u64)hi << 32);
    __hip_atomic_store((u64*)p, v, __ATOMIC_RELAXED, __HIP_MEMORY_SCOPE_SYSTEM);
}
__device__ __forceinline__ bf16x8 ld16_sys(const unsigned short* p) {
    u64 lo = __hip_atomic_load((const u64*)p,       __ATOMIC_RELAXED, __HIP_MEMORY_SCOPE_SYSTEM);
    u64 hi = __hip_atomic_load((const u64*)(p + 4), __ATOMIC_RELAXED, __HIP_MEMORY_SCOPE_SYSTEM);
    union { u64 q[2]; bf16x8 v; } u; u.q[0] = lo; u.q[1] = hi;
    return u.v;
}

__global__ void init_out_kernel(float* out, int* flags) {
    int i = blockIdx.x * blockDim.x + threadIdx.x;
    if (i < HH + 1) out[i] = 0.0f;
    if (i < NGRP * NMEM) flags[i] = 0;
}

// Pre-shuffle weights into MFMA A-fragment order, bf16 (layout verified R2-R7).
__global__ void convert_weights(const float* __restrict__ Wih, const float* __restrict__ Whh,
                                const float* __restrict__ Wout,
                                unsigned short* __restrict__ wsA, unsigned short* __restrict__ wsO) {
    int gid = blockIdx.x * blockDim.x + threadIdx.x;
    if (gid < NMT * NKT * 64) {
        int lane = gid & 63, tile = gid >> 6;
        int kt = tile % NKT, mt = tile / NKT;
        int row = mt * 16 + (lane & 15);
        int kb  = kt * 32 + (lane >> 4) * 8;
        unsigned short o[8];
#pragma unroll
        for (int j = 0; j < 8; ++j) {
            int k = kb + j;
            float v = (k < EE) ? Wih[row * EE + k] : Whh[row * HH + (k - EE)];
            o[j] = f2bf(v);
        }
        uint4 pk;
        pk.x = o[0] | ((unsigned)o[1] << 16); pk.y = o[2] | ((unsigned)o[3] << 16);
        pk.z = o[4] | ((unsigned)o[5] << 16); pk.w = o[6] | ((unsigned)o[7] << 16);
        *(uint4*)(wsA + (size_t)gid * 8) = pk;
    } else {
        int g2 = gid - NMT * NKT * 64;
        if (g2 < NMT * NKT_O * 64) {
            int lane = g2 & 63, tile = g2 >> 6;
            int kt = tile % NKT_O, mt = tile / NKT_O;
            int row = mt * 16 + (lane & 15);
            int ub  = kt * 32 + (lane >> 4) * 8;
            unsigned short o[8];
#pragma unroll
            for (int j = 0; j < 8; ++j)
                o[j] = (row < LL) ? f2bf(Wout[row * HH + ub + j]) : (unsigned short)0;
            uint4 pk;
            pk.x = o[0] | ((unsigned)o[1] << 16); pk.y = o[2] | ((unsigned)o[3] << 16);
            pk.z = o[4] | ((unsigned)o[5] << 16); pk.w = o[6] | ((unsigned)o[7] << 16);
            *(uint4*)(wsO + (size_t)g2 * 8) = pk;
        }
    }
}

// 8-way split LSTM, software-pipelined: x-part of step t+1 computed during the
// wait for partners' h(t). Flag posts last; staging/prefetch at iter head.
__launch_bounds__(NT, 2)
__global__ void lstm_group_kernel(
    const int* __restrict__ tokens, const int* __restrict__ lengths,
    const int* __restrict__ labels, const float* __restrict__ emb,
    const float* __restrict__ bih,  const float* __restrict__ bhh,
    const float* __restrict__ bout,
    const unsigned short* __restrict__ wsA, const unsigned short* __restrict__ wsO,
    unsigned short* __restrict__ ghf, int* __restrict__ flags,
    float* __restrict__ out)
{
    __shared__ __align__(16) unsigned short wlds[8 * 12 * 64 * 8];   // 96 KB A-frags
    __shared__ __align__(16) unsigned short xfS[4 * 4 * 64 * 8];     // 16 KB x B-frags (single)
    __shared__ __align__(16) unsigned short hf[2 * 4 * 64 * 8];      // 8 KB own-h B-frags (dbuf)
    __shared__ float redm[8][16];
    __shared__ float reds[8][16];
    __shared__ int   labv[SEQG];
    __shared__ int   ready_s;

    const int tid = threadIdx.x;
    const int w   = tid >> 6;
    const int l   = tid & 63;
    const int lq  = l >> 4;
    const int ls  = l & 15;
    const int jj  = w >> 2;        // row half (0/1)
    const int cg  = w & 3;         // col group (16 seqs)
    const int grp = blockIdx.x & (NGRP - 1);
    const int m   = blockIdx.x >> 5;
    const int n0  = grp * SEQG;

    int* const flagBase = flags + grp * NMEM;

    int maxlen = lengths[n0 + l];
#pragma unroll
    for (int s = 1; s < 64; s <<= 1) maxlen = max(maxlen, __shfl_xor(maxlen, s, 64));
    const int len_s = lengths[n0 + cg * 16 + ls];

    if (tid < SEQG) labv[tid] = labels[n0 + tid];
    if (tid == 0) ready_s = 0;

    // biases in registers (per-lane: gate rows for this wave's acc slots)
    f32x4 biasv[4];
#pragma unroll
    for (int g = 0; g < 4; ++g)
#pragma unroll
        for (int r = 0; r < 4; ++r) {
            int row = 256 * g + 32 * m + 16 * jj + 4 * lq + r;
            biasv[g][r] = bih[row] + bhh[row];
        }

    // ---- one-time: this member's A-frags (8 mt x 12 kt) -> LDS ----
    for (int idx = tid; idx < 8 * 12 * 64; idx += NT) {
        int mtl = idx / 768;
        int rem = idx - mtl * 768;
        int kt = rem >> 6, l2 = rem & 63;
        int g = mtl >> 1, j2 = mtl & 1;
        int gmt = 16 * g + 2 * m + j2;
        *(uint4*)&wlds[(size_t)idx * 8] =
            *(const uint4*)(wsA + ((size_t)(gmt * NKT + kt) * 64 + l2) * 8);
    }

    // zero hf buf0 + ghf parity0 slice (h(0) = 0)
    if (tid < 256) {
        uint4 z = {0, 0, 0, 0};
        *(uint4*)&hf[(size_t)tid * 8] = z;
        size_t base = ((size_t)((grp * NMEM + m) * 2 + 0) * 4) * 512 + (size_t)tid * 8;
        st8_sys(&ghf[base], 0, 0);
        st8_sys(&ghf[base + 4], 0, 0);
    }

    // x staging map: thread -> (seq, 16-dim octet)
    const int xs_s   = tid & 63;
    const int xs_oct = tid >> 6;

    auto stageX = [&](const f32x4* xv) {
#pragma unroll
        for (int dc = 0; dc < 4; ++dc) {
            int d0 = 16 * xs_oct + 4 * dc;
            int kt = d0 >> 5, cgs = xs_s >> 4;
            int lanep = (xs_s & 15) + 16 * ((d0 >> 3) & 3);
            uint2 pk;
            pk.x = f2bf(xv[dc][0]) | ((unsigned)f2bf(xv[dc][1]) << 16);
            pk.y = f2bf(xv[dc][2]) | ((unsigned)f2bf(xv[dc][3]) << 16);
            *(uint2*)&xfS[(size_t)((kt * 4 + cgs) * 64 + lanep) * 8 + (d0 & 4)] = pk;
        }
    };

    // stage x(0)
    {
        int tok = tokens[(n0 + xs_s) * TT + 0];
        const float* er = emb + (size_t)tok * EE + 16 * xs_oct;
        f32x4 x0[4];
#pragma unroll
        for (int dc = 0; dc < 4; ++dc) x0[dc] = *(const f32x4*)(er + 4 * dc);
        stageX(x0);
    }
    __syncthreads();   // drains ghf zero stores + x(0) staging + wlds
    if (tid == 0)
        __hip_atomic_store(&flagBase[m], 1, __ATOMIC_RELAXED, __HIP_MEMORY_SCOPE_SYSTEM);

    // prefetch x(1)
    f32x4 xv[4];
    if (maxlen > 1) {
        int tok = tokens[(n0 + xs_s) * TT + 1];
        const float* er = emb + (size_t)tok * EE + 16 * xs_oct;
#pragma unroll
        for (int dc = 0; dc < 4; ++dc) xv[dc] = *(const f32x4*)(er + 4 * dc);
    }

    // acc = bias + xpart(x(0))
    f32x4 acc[4], accN[4];
#pragma unroll
    for (int g = 0; g < 4; ++g) acc[g] = biasv[g];
#pragma unroll
    for (int kt = 0; kt < 4; ++kt) {
        const bf16x8 bx = *(const bf16x8*)&xfS[(size_t)((kt * 4 + cg) * 64 + l) * 8];
#pragma unroll
        for (int g = 0; g < 4; ++g)
            acc[g] = __builtin_amdgcn_mfma_f32_16x16x32_bf16(
                *(const bf16x8*)&wlds[(size_t)(((2 * g + jj) * 12 + kt) * 64 + l) * 8],
                bx, acc[g], 0, 0, 0);
    }
    __syncthreads();   // xfS reads done; iter 0 may restage

    // relay wait: wave0 polls flags; other waves spin on LDS
    auto relay_wait = [&](int need) {
        if (w == 0) {
            int f;
            do {
                f = 0x7fffffff;
                if (l < NMEM)
                    f = __hip_atomic_load(&flagBase[l], __ATOMIC_RELAXED, __HIP_MEMORY_SCOPE_SYSTEM);
                f = min(f, __shfl_xor(f, 1, 64));
                f = min(f, __shfl_xor(f, 2, 64));
                f = min(f, __shfl_xor(f, 4, 64));
                f = __shfl(f, 0, 64);
                if (f < need) __builtin_amdgcn_s_sleep(2);
            } while (f < need);
            __hip_atomic_store(&ready_s, need, __ATOMIC_RELEASE, __HIP_MEMORY_SCOPE_WORKGROUP);
        } else {
            while (__hip_atomic_load(&ready_s, __ATOMIC_ACQUIRE, __HIP_MEMORY_SCOPE_WORKGROUP) < need)
                __builtin_amdgcn_s_sleep(1);
        }
    };

    float c_reg[4], h_reg[4];
#pragma unroll
    for (int r = 0; r < 4; ++r) { c_reg[r] = 0.0f; h_reg[r] = 0.0f; }

    // h publish mapping: unit u = 16*jj + 4*lq + r in member's 32-k tile
    const int u8      = 2 * jj + (lq >> 1);
    const int lanep_h = 16 * u8 + ls;
    const int joff_h  = 4 * (lq & 1);
    const size_t gb0  = ((size_t)((grp * NMEM + m) * 2 + 0) * 4 + cg) * 512 + (size_t)lanep_h * 8 + joff_h;
    const size_t gb1  = gb0 + 4 * 512;

    // ---- recurrence (steady state: xpart(t) already in acc) ----
    for (int t = 0; t < maxlen; ++t) {
        const int cur = t & 1, nxt = cur ^ 1;
        const bool doX = (t + 1 < maxlen);

        // head: stage x(t+1) from regs (partner-independent)
        if (doX) stageX(xv);
        // own-h B-frag (hf[cur] written before last barrier)
        const bf16x8 bo = *(const bf16x8*)&hf[(size_t)((cur * 4 + cg) * 64 + l) * 8];
        if (doX) __syncthreads();   // staging visible; cheap (no vmem pending)

        // prefetch x(t+2) (drained at barrier B, a full iter away)
        if (t + 2 < maxlen) {
            int tok = tokens[(n0 + xs_s) * TT + t + 2];
            const float* er = emb + (size_t)tok * EE + 16 * xs_oct;
#pragma unroll
            for (int dc = 0; dc < 4; ++dc) xv[dc] = *(const f32x4*)(er + 4 * dc);
        }

        // xpart(t+1) into accN — fills the wait window
        if (doX) {
#pragma unroll
            for (int g = 0; g < 4; ++g) accN[g] = biasv[g];
#pragma unroll
            for (int kt = 0; kt < 4; ++kt) {
                const bf16x8 bx = *(const bf16x8*)&xfS[(size_t)((kt * 4 + cg) * 64 + l) * 8];
#pragma unroll
                for (int g = 0; g < 4; ++g)
                    accN[g] = __builtin_amdgcn_mfma_f32_16x16x32_bf16(
                        *(const bf16x8*)&wlds[(size_t)(((2 * g + jj) * 12 + kt) * 64 + l) * 8],
                        bx, accN[g], 0, 0, 0);
            }
        }

        // wait for all members' h(t)
        relay_wait(t + 1);

        // partner B-frag loads (L3)
        bf16x8 bp[7];
#pragma unroll
        for (int i = 0; i < 7; ++i) {
            int p = i + (i >= m ? 1 : 0);
            size_t b = ((size_t)((grp * NMEM + p) * 2 + cur) * 4 + cg) * 512;
            bp[i] = ld16_sys(&ghf[b + (size_t)l * 8]);
        }

        // own-h part first (hides partner-load latency)
#pragma unroll
        for (int g = 0; g < 4; ++g)
            acc[g] = __builtin_amdgcn_mfma_f32_16x16x32_bf16(
                *(const bf16x8*)&wlds[(size_t)(((2 * g + jj) * 12 + 4 + m) * 64 + l) * 8],
                bo, acc[g], 0, 0, 0);
        // partner-h parts
#pragma unroll
        for (int i = 0; i < 7; ++i) {
            int p = i + (i >= m ? 1 : 0);
            int kt = 4 + p;
#pragma unroll
            for (int g = 0; g < 4; ++g)
                acc[g] = __builtin_amdgcn_mfma_f32_16x16x32_bf16(
                    *(const bf16x8*)&wlds[(size_t)(((2 * g + jj) * 12 + kt) * 64 + l) * 8],
                    bp[i], acc[g], 0, 0, 0);
        }

        // in-register cell update
        const bool live = (t < len_s);
#pragma unroll
        for (int r = 0; r < 4; ++r) {
            if (live) {
                float ig = sigf(acc[0][r]);
                float fg = sigf(acc[1][r]);
                float gg = tanh_fast(acc[2][r]);
                float og = sigf(acc[3][r]);
                float cc = fg * c_reg[r] + ig * gg;
                c_reg[r] = cc;
                h_reg[r] = og * tanh_fast(cc);
            }
        }

        // carry pipelined xpart
        if (doX) {
#pragma unroll
            for (int g = 0; g < 4; ++g) acc[g] = accN[g];
        }

        // publish h(t+1): LDS nxt + ghf (system store), parity (t+1)&1
        {
            uint2 hp;
            hp.x = f2bf(h_reg[0]) | ((unsigned)f2bf(h_reg[1]) << 16);
            hp.y = f2bf(h_reg[2]) | ((unsigned)f2bf(h_reg[3]) << 16);
            *(uint2*)&hf[(size_t)((nxt * 4 + cg) * 64 + lanep_h) * 8 + joff_h] = hp;
            st8_sys(&ghf[((t + 1) & 1) ? gb1 : gb0], hp.x, hp.y);
        }

        __syncthreads();   // barrier B: drains ghf stores (+ x prefetch loads)
        if (tid == 0)
            __hip_atomic_store(&flagBase[m], t + 2, __ATOMIC_RELAXED, __HIP_MEMORY_SCOPE_SYSTEM);
    }

    // ---- epilogue 1: embeds = mean(c_f) for own 32 units ----
#pragma unroll
    for (int r = 0; r < 4; ++r) {
        float v = c_reg[r];
        v += __shfl_xor(v, 1, 64);
        v += __shfl_xor(v, 2, 64);
        v += __shfl_xor(v, 4, 64);
        v += __shfl_xor(v, 8, 64);
        if (ls == 0)
            atomicAdd(&out[32 * m + 16 * jj + 4 * lq + r], v * (1.0f / NSEQ));
    }

    // ---- epilogue 2 (member 0): logits GEMM + log-softmax ----
    if (m == 0) {
        relay_wait(maxlen + 1);
        const int fin = maxlen & 1;
        float* lg = (float*)wlds;            // reuse: 16 seqs x 1024 logits
        float lossAcc = 0.0f;

        for (int cgo = 0; cgo < 4; ++cgo) {
            bf16x8 bq[8];
#pragma unroll
            for (int p = 0; p < 8; ++p) {
                size_t b = ((size_t)((grp * NMEM + p) * 2 + fin) * 4 + cgo) * 512;
                bq[p] = ld16_sys(&ghf[b + (size_t)l * 8]);
            }
            __syncthreads();
#pragma unroll
            for (int i = 0; i < 8; ++i) {
                int mt = 8 * w + i;
                f32x4 a = {0.0f, 0.0f, 0.0f, 0.0f};
#pragma unroll
                for (int p = 0; p < 8; ++p)
                    a = __builtin_amdgcn_mfma_f32_16x16x32_bf16(
                        *(const bf16x8*)(wsO + ((size_t)(mt * NKT_O + p) * 64 + l) * 8),
                        bq[p], a, 0, 0, 0);
#pragma unroll
                for (int r = 0; r < 4; ++r) {
                    int cls = 16 * mt + 4 * lq + r;
                    lg[(size_t)ls * 1024 + cls] = (cls < LL) ? (a[r] + bout[cls]) : -INFINITY;
                }
            }
            __syncthreads();
            const int s2 = tid >> 5;
            const int i2 = tid & 31;
            const float* row = &lg[(size_t)s2 * 1024];
            float mx = -INFINITY;
#pragma unroll
            for (int k = 0; k < 32; ++k) mx = fmaxf(mx, row[i2 + 32 * k]);
            mx = fmaxf(mx, __shfl_xor(mx, 1, 64));
            mx = fmaxf(mx, __shfl_xor(mx, 2, 64));
            mx = fmaxf(mx, __shfl_xor(mx, 4, 64));
            mx = fmaxf(mx, __shfl_xor(mx, 8, 64));
            mx = fmaxf(mx, __shfl_xor(mx, 16, 64));
            float sm = 0.0f;
#pragma unroll
            for (int k = 0; k < 32; ++k) sm += __expf(row[i2 + 32 * k] - mx);
            sm += __shfl_xor(sm, 1, 64);
            sm += __shfl_xor(sm, 2, 64);
            sm += __shfl_xor(sm, 4, 64);
            sm += __shfl_xor(sm, 8, 64);
            sm += __shfl_xor(sm, 16, 64);
            if (i2 == 0) {
                int lab = labv[cgo * 16 + s2];
                float lp = row[lab] - mx - __logf(sm);
                lossAcc += -lp;
            }
        }
        if ((tid & 31) == 0)
            atomicAdd(&out[HH], lossAcc * (1.0f / NSEQ));
    }
}

extern "C" void kernel_launch(void* const* d_in, const int* in_sizes, int n_in,
                              void* d_out, int out_size, void* d_ws, size_t ws_size,
                              hipStream_t stream)
{
    const int*   tokens  = (const int*)d_in[0];
    const int*   lengths = (const int*)d_in[1];
    const int*   labels  = (const int*)d_in[2];
    const float* emb     = (const float*)d_in[3];
    const float* Wih     = (const float*)d_in[4];
    const float* Whh     = (const float*)d_in[5];
    const float* bih     = (const float*)d_in[6];
    const float* bhh     = (const float*)d_in[7];
    const float* Wout    = (const float*)d_in[8];
    const float* bout    = (const float*)d_in[9];
    float* out = (float*)d_out;

    unsigned short* wsA  = (unsigned short*)d_ws;
    unsigned short* wsO  = wsA + WSA_ELEMS;
    unsigned short* ghf  = wsO + WSO_ELEMS;
    int*            flg  = (int*)(ghf + GHF_SHORTS);

    hipLaunchKernelGGL(init_out_kernel, dim3(1), dim3(512), 0, stream, out, flg);
    {
        int nthr = NMT * NKT * 64 + NMT * NKT_O * 64;
        hipLaunchKernelGGL(convert_weights, dim3((nthr + 255) / 256), dim3(256), 0, stream,
                           Wih, Whh, Wout, wsA, wsO);
    }
    hipLaunchKernelGGL(lstm_group_kernel, dim3(NGRP * NMEM), dim3(NT), 0, stream,
                       tokens, lengths, labels, emb, bih, bhh, bout, wsA, wsO, ghf, flg, out);
}